// Round 1
// baseline (802.615 us; speedup 1.0000x reference)
//
#include <hip/hip_runtime.h>

// MoE layer: router top-2 + per-expert SwiGLU FFN + weighted combine + LayerNorm.
// Tokens = 4096, D_MODEL=1024, D_FFN=2048, E=8, TOPK=2. All fp32 I/O, bf16 MFMA inside.
//
// Workspace layout (assumes ws_size >= ~43 MB):
//   [0..31]        counts[8]  (int)
//   [32..63]       offsets[8] (int)
//   [256..]        tok_list[8*4096] (int)     128 KB
//   next           wt_list [8*4096] (float)   128 KB
//   next           xb [4096*1024] bf16          8 MB
//   next           H  [(8192+128)*2048] bf16   ~34 MB

#define D_MODEL 1024
#define D_FFN   2048
#define N_EXP   8
#define TOKENS  4096
#define LISTCAP 4096

typedef __bf16 bf16x8 __attribute__((ext_vector_type(8)));
typedef float  f32x4  __attribute__((ext_vector_type(4)));

__device__ __forceinline__ ushort f2bf(float f) {
  union { float f; unsigned u; } v; v.f = f;
  unsigned u = v.u;
  u += 0x7fffu + ((u >> 16) & 1u);   // round-to-nearest-even
  return (ushort)(u >> 16);
}

// ---------------- Router: logits, top-2 softmax, expert lists, x -> bf16 ----
__global__ __launch_bounds__(64) void router_kernel(
    const float* __restrict__ x, const float* __restrict__ wr,
    ushort* __restrict__ xb, int* __restrict__ counts,
    int* __restrict__ tok_list, float* __restrict__ wt_list)
{
  const int token = blockIdx.x;
  const int lane  = threadIdx.x;
  const float* xr = x + (size_t)token * D_MODEL;

  float xv[16];
  #pragma unroll
  for (int j = 0; j < 16; ++j) xv[j] = xr[j * 64 + lane];

  ushort* xbr = xb + (size_t)token * D_MODEL;
  #pragma unroll
  for (int j = 0; j < 16; ++j) xbr[j * 64 + lane] = f2bf(xv[j]);

  float logit[N_EXP];
  #pragma unroll
  for (int e = 0; e < N_EXP; ++e) {
    const float* w = wr + e * D_MODEL;
    float p = 0.f;
    #pragma unroll
    for (int j = 0; j < 16; ++j) p += xv[j] * w[j * 64 + lane];
    #pragma unroll
    for (int o = 32; o > 0; o >>= 1) p += __shfl_xor(p, o, 64);
    logit[e] = p;
  }

  if (lane == 0) {
    float v0 = -1e30f, v1 = -1e30f; int i0 = 0, i1 = 0;
    #pragma unroll
    for (int e = 0; e < N_EXP; ++e) {
      float v = logit[e];
      if (v > v0)      { v1 = v0; i1 = i0; v0 = v; i0 = e; }
      else if (v > v1) { v1 = v; i1 = e; }
    }
    float t  = expf(v1 - v0);           // stable 2-way softmax
    float w0 = 1.f / (1.f + t);
    float w1 = t   / (1.f + t);
    int p0 = atomicAdd(&counts[i0], 1);
    tok_list[i0 * LISTCAP + p0] = token;
    wt_list[i0 * LISTCAP + p0] = w0;
    int p1 = atomicAdd(&counts[i1], 1);
    tok_list[i1 * LISTCAP + p1] = token;
    wt_list[i1 * LISTCAP + p1] = w1;
  }
}

// ---------------- Exclusive prefix over expert counts ----------------------
__global__ void prefix_kernel(const int* __restrict__ counts, int* __restrict__ offsets)
{
  if (threadIdx.x == 0 && blockIdx.x == 0) {
    int s = 0;
    for (int e = 0; e < N_EXP; ++e) { offsets[e] = s; s += counts[e]; }
  }
}

// ---------------- Gate+Up grouped GEMM + SwiGLU -> H (bf16) ----------------
// grid (16 n-tiles, 32 m-tiles, 8 experts), 256 threads, 128x128 tile, BK=64
__global__ __launch_bounds__(256, 2) void gateup_kernel(
    const ushort* __restrict__ xb, const float* __restrict__ wg,
    const float* __restrict__ wu, const int* __restrict__ counts,
    const int* __restrict__ offsets, const int* __restrict__ tok_list,
    ushort* __restrict__ H)
{
  const int e  = blockIdx.z;
  const int Ne = counts[e];
  const int m0 = blockIdx.y * 128;
  if (m0 >= Ne) return;
  const int n0 = blockIdx.x * 128;

  __shared__ ushort As[128][80];   // +16 pad: 160B row stride, 16B aligned
  __shared__ ushort Bg[128][80];
  __shared__ ushort Bu[128][80];
  __shared__ int tok_s[128];

  const int tid = threadIdx.x;
  if (tid < 128) {
    int i = m0 + tid;
    tok_s[tid] = tok_list[e * LISTCAP + (i < Ne ? i : 0)];
  }
  __syncthreads();

  const int wave = tid >> 6;
  const int lane = tid & 63;
  const int wm   = (wave >> 1) * 64;
  const int wn   = (wave & 1) * 64;
  const int lrow = lane & 15;
  const int lk   = (lane >> 4) * 8;

  f32x4 accg[4][4], accu[4][4];
  #pragma unroll
  for (int i = 0; i < 4; ++i)
    #pragma unroll
    for (int j = 0; j < 4; ++j) {
      accg[i][j] = f32x4{0.f, 0.f, 0.f, 0.f};
      accu[i][j] = f32x4{0.f, 0.f, 0.f, 0.f};
    }

  const size_t wbase = ((size_t)e * D_FFN + n0) * D_MODEL;

  for (int k0 = 0; k0 < D_MODEL; k0 += 64) {
    // stage A (gathered token rows of xb), 16B per thread per round
    #pragma unroll
    for (int r = 0; r < 4; ++r) {
      int idx = tid + r * 256;
      int row = idx >> 3;
      int c8  = (idx & 7) * 8;
      const ushort* src = xb + (size_t)tok_s[row] * D_MODEL + k0 + c8;
      *(uint4*)(&As[row][c8]) = *(const uint4*)src;
    }
    // stage Bg/Bu: fp32 -> bf16 on the fly
    #pragma unroll
    for (int r = 0; r < 8; ++r) {
      int idx = tid + r * 256;
      int row = idx >> 4;
      int c4  = (idx & 15) * 4;
      const size_t off = wbase + (size_t)row * D_MODEL + k0 + c4;
      const float4 g = *(const float4*)(wg + off);
      const float4 u = *(const float4*)(wu + off);
      ushort4 gb; gb.x = f2bf(g.x); gb.y = f2bf(g.y); gb.z = f2bf(g.z); gb.w = f2bf(g.w);
      ushort4 ub; ub.x = f2bf(u.x); ub.y = f2bf(u.y); ub.z = f2bf(u.z); ub.w = f2bf(u.w);
      *(ushort4*)(&Bg[row][c4]) = gb;
      *(ushort4*)(&Bu[row][c4]) = ub;
    }
    __syncthreads();

    #pragma unroll
    for (int kk = 0; kk < 64; kk += 32) {
      bf16x8 af[4], bgf[4], buf[4];
      #pragma unroll
      for (int mi = 0; mi < 4; ++mi)
        af[mi] = *(const bf16x8*)(&As[wm + mi * 16 + lrow][kk + lk]);
      #pragma unroll
      for (int ni = 0; ni < 4; ++ni) {
        bgf[ni] = *(const bf16x8*)(&Bg[wn + ni * 16 + lrow][kk + lk]);
        buf[ni] = *(const bf16x8*)(&Bu[wn + ni * 16 + lrow][kk + lk]);
      }
      #pragma unroll
      for (int mi = 0; mi < 4; ++mi)
        #pragma unroll
        for (int ni = 0; ni < 4; ++ni) {
          accg[mi][ni] = __builtin_amdgcn_mfma_f32_16x16x32_bf16(af[mi], bgf[ni], accg[mi][ni], 0, 0, 0);
          accu[mi][ni] = __builtin_amdgcn_mfma_f32_16x16x32_bf16(af[mi], buf[ni], accu[mi][ni], 0, 0, 0);
        }
    }
    __syncthreads();
  }

  // SwiGLU epilogue -> H (bf16). C/D layout: col = lane&15, row = (lane>>4)*4 + reg.
  const int row_base = offsets[e] + m0;
  #pragma unroll
  for (int mi = 0; mi < 4; ++mi)
    #pragma unroll
    for (int ni = 0; ni < 4; ++ni)
      #pragma unroll
      for (int r4 = 0; r4 < 4; ++r4) {
        int m = wm + mi * 16 + (lane >> 4) * 4 + r4;
        if (m0 + m < Ne) {
          int n = wn + ni * 16 + (lane & 15);
          float g = accg[mi][ni][r4];
          float u = accu[mi][ni][r4];
          float h = g / (1.f + __expf(-g)) * u;   // silu(g) * u
          H[(size_t)(row_base + m) * D_FFN + (n0 + n)] = f2bf(h);
        }
      }
}

// ---------------- Down grouped GEMM + weighted scatter ---------------------
// grid (8 n-tiles, 32 m-tiles, 8 experts), 256 threads, 128x128 tile, BK=64
__global__ __launch_bounds__(256, 2) void down_kernel(
    const ushort* __restrict__ H, const float* __restrict__ wd,
    const int* __restrict__ counts, const int* __restrict__ offsets,
    const int* __restrict__ tok_list, const float* __restrict__ wt_list,
    float* __restrict__ out)
{
  const int e  = blockIdx.z;
  const int Ne = counts[e];
  const int m0 = blockIdx.y * 128;
  if (m0 >= Ne) return;
  const int n0 = blockIdx.x * 128;

  __shared__ ushort As[128][80];
  __shared__ ushort Bd[128][80];
  __shared__ int   tok_s[128];
  __shared__ float wt_s[128];

  const int tid = threadIdx.x;
  if (tid < 128) {
    int i  = m0 + tid;
    int ok = (i < Ne);
    tok_s[tid] = tok_list[e * LISTCAP + (ok ? i : 0)];
    wt_s[tid]  = ok ? wt_list[e * LISTCAP + i] : 0.f;
  }
  __syncthreads();

  const int wave = tid >> 6;
  const int lane = tid & 63;
  const int wm   = (wave >> 1) * 64;
  const int wn   = (wave & 1) * 64;
  const int lrow = lane & 15;
  const int lk   = (lane >> 4) * 8;
  const int row_base = offsets[e] + m0;

  f32x4 acc[4][4];
  #pragma unroll
  for (int i = 0; i < 4; ++i)
    #pragma unroll
    for (int j = 0; j < 4; ++j) acc[i][j] = f32x4{0.f, 0.f, 0.f, 0.f};

  const size_t wdbase = ((size_t)e * D_MODEL + n0) * D_FFN;

  for (int k0 = 0; k0 < D_FFN; k0 += 64) {
    #pragma unroll
    for (int r = 0; r < 4; ++r) {
      int idx = tid + r * 256;
      int row = idx >> 3;
      int c8  = (idx & 7) * 8;
      const ushort* src = H + (size_t)(row_base + row) * D_FFN + k0 + c8;
      *(uint4*)(&As[row][c8]) = *(const uint4*)src;
    }
    #pragma unroll
    for (int r = 0; r < 8; ++r) {
      int idx = tid + r * 256;
      int row = idx >> 4;
      int c4  = (idx & 15) * 4;
      const float4 d = *(const float4*)(wd + wdbase + (size_t)row * D_FFN + k0 + c4);
      ushort4 db; db.x = f2bf(d.x); db.y = f2bf(d.y); db.z = f2bf(d.z); db.w = f2bf(d.w);
      *(ushort4*)(&Bd[row][c4]) = db;
    }
    __syncthreads();

    #pragma unroll
    for (int kk = 0; kk < 64; kk += 32) {
      bf16x8 af[4], bdf[4];
      #pragma unroll
      for (int mi = 0; mi < 4; ++mi)
        af[mi] = *(const bf16x8*)(&As[wm + mi * 16 + lrow][kk + lk]);
      #pragma unroll
      for (int ni = 0; ni < 4; ++ni)
        bdf[ni] = *(const bf16x8*)(&Bd[wn + ni * 16 + lrow][kk + lk]);
      #pragma unroll
      for (int mi = 0; mi < 4; ++mi)
        #pragma unroll
        for (int ni = 0; ni < 4; ++ni)
          acc[mi][ni] = __builtin_amdgcn_mfma_f32_16x16x32_bf16(af[mi], bdf[ni], acc[mi][ni], 0, 0, 0);
    }
    __syncthreads();
  }

  // weighted scatter: exactly 2 commutative fp32 atomic adds per out element
  #pragma unroll
  for (int mi = 0; mi < 4; ++mi)
    #pragma unroll
    for (int ni = 0; ni < 4; ++ni)
      #pragma unroll
      for (int r4 = 0; r4 < 4; ++r4) {
        int m = wm + mi * 16 + (lane >> 4) * 4 + r4;
        if (m0 + m < Ne) {
          int n = wn + ni * 16 + (lane & 15);
          float v = acc[mi][ni][r4] * wt_s[m];
          atomicAdd(&out[(size_t)tok_s[m] * D_MODEL + (n0 + n)], v);
        }
      }
}

// ---------------- LayerNorm (in-place on d_out) ----------------------------
__global__ __launch_bounds__(256) void ln_kernel(
    float* __restrict__ out, const float* __restrict__ gamma,
    const float* __restrict__ beta)
{
  const int row = blockIdx.x;
  const int t   = threadIdx.x;
  float* rp = out + (size_t)row * D_MODEL;

  float4 v = ((const float4*)rp)[t];
  float s = v.x + v.y + v.z + v.w;
  #pragma unroll
  for (int o = 32; o > 0; o >>= 1) s += __shfl_xor(s, o, 64);

  __shared__ float red[4];
  const int wave = t >> 6, lane = t & 63;
  if (lane == 0) red[wave] = s;
  __syncthreads();
  float mean = (red[0] + red[1] + red[2] + red[3]) * (1.f / D_MODEL);

  float dx = v.x - mean, dy = v.y - mean, dz = v.z - mean, dw = v.w - mean;
  float ss = dx * dx + dy * dy + dz * dz + dw * dw;
  #pragma unroll
  for (int o = 32; o > 0; o >>= 1) ss += __shfl_xor(ss, o, 64);
  __syncthreads();
  if (lane == 0) red[wave] = ss;
  __syncthreads();
  float var = (red[0] + red[1] + red[2] + red[3]) * (1.f / D_MODEL);
  float rs  = rsqrtf(var + 1e-5f);

  float4 g = ((const float4*)gamma)[t];
  float4 b = ((const float4*)beta)[t];
  float4 o4;
  o4.x = dx * rs * g.x + b.x;
  o4.y = dy * rs * g.y + b.y;
  o4.z = dz * rs * g.z + b.z;
  o4.w = dw * rs * g.w + b.w;
  ((float4*)rp)[t] = o4;
}

// ---------------- Launch ----------------------------------------------------
extern "C" void kernel_launch(void* const* d_in, const int* in_sizes, int n_in,
                              void* d_out, int out_size, void* d_ws, size_t ws_size,
                              hipStream_t stream) {
  const float* x        = (const float*)d_in[0];
  const float* w_router = (const float*)d_in[1];
  const float* w_gate   = (const float*)d_in[2];
  const float* w_up     = (const float*)d_in[3];
  const float* w_down   = (const float*)d_in[4];
  const float* ln_gamma = (const float*)d_in[5];
  const float* ln_beta  = (const float*)d_in[6];
  float* out = (float*)d_out;

  char* ws       = (char*)d_ws;
  int*   counts   = (int*)ws;            // 8 ints
  int*   offsets  = counts + 8;          // 8 ints
  int*   tok_list = (int*)(ws + 256);                       // 8*4096 ints
  float* wt_list  = (float*)(ws + 256 + LISTCAP * N_EXP * 4);
  ushort* xb      = (ushort*)(ws + 256 + LISTCAP * N_EXP * 8);
  ushort* H       = xb + (size_t)TOKENS * D_MODEL;          // (8192+128) x 2048 bf16

  hipMemsetAsync(counts, 0, 64, stream);
  hipMemsetAsync(out, 0, (size_t)TOKENS * D_MODEL * sizeof(float), stream);

  router_kernel<<<TOKENS, 64, 0, stream>>>(x, w_router, xb, counts, tok_list, wt_list);
  prefix_kernel<<<1, 64, 0, stream>>>(counts, offsets);
  gateup_kernel<<<dim3(D_FFN / 128, 32, N_EXP), 256, 0, stream>>>(
      xb, w_gate, w_up, counts, offsets, tok_list, H);
  down_kernel<<<dim3(D_MODEL / 128, 32, N_EXP), 256, 0, stream>>>(
      H, w_down, counts, offsets, tok_list, wt_list, out);
  ln_kernel<<<TOKENS, 256, 0, stream>>>(out, ln_gamma, ln_beta);
}

// Round 2
// 502.656 us; speedup vs baseline: 1.5967x; 1.5967x over previous
//
#include <hip/hip_runtime.h>

// MoE layer: router top-2 + per-expert SwiGLU FFN + weighted combine + LayerNorm.
// Tokens=4096, D_MODEL=1024, D_FFN=2048, E=8, TOPK=2. fp32 I/O, bf16 MFMA inside.
//
// Fast path (ws_size >= ~152MB):
//   router -> prefix -> gather(x->Xg bf16, expert-sorted) -> convert w{g,u,d}->bf16
//   -> gateup GEMM (global_load_lds + XOR-swizzled LDS) -> down GEMM -> combine+LN.
// Fallback path (small ws): round-1 pipeline (convert-in-kernel, atomic scatter).

#define D_MODEL 1024
#define D_FFN   2048
#define N_EXP   8
#define TOKENS  4096
#define LISTCAP 4096
#define ROWS_PAD 8320   // 8192 rows + 128 slack (tile overrun reads)

typedef __bf16 bf16x8 __attribute__((ext_vector_type(8)));
typedef float  f32x4  __attribute__((ext_vector_type(4)));

__device__ __forceinline__ ushort f2bf(float f) {
  union { float f; unsigned u; } v; v.f = f;
  unsigned u = v.u;
  u += 0x7fffu + ((u >> 16) & 1u);   // round-to-nearest-even
  return (ushort)(u >> 16);
}
__device__ __forceinline__ float bf2f(ushort h) {
  union { unsigned u; float f; } v; v.u = ((unsigned)h) << 16; return v.f;
}
__device__ __forceinline__ void gl2lds16(const ushort* g, ushort* l) {
  __builtin_amdgcn_global_load_lds(
      (const __attribute__((address_space(1))) unsigned int*)g,
      (__attribute__((address_space(3))) unsigned int*)l, 16, 0, 0);
}

// ======================= shared: prefix =====================================
__global__ void prefix_kernel(const int* __restrict__ counts, int* __restrict__ offsets)
{
  if (threadIdx.x == 0 && blockIdx.x == 0) {
    int s = 0;
    for (int e = 0; e < N_EXP; ++e) { offsets[e] = s; s += counts[e]; }
  }
}

// ======================= FAST PATH ==========================================

// Router: logits, top-2 softmax, expert lists + per-token slots/weights.
__global__ __launch_bounds__(64) void router2_kernel(
    const float* __restrict__ x, const float* __restrict__ wr,
    int* __restrict__ counts, int* __restrict__ tok_list,
    int* __restrict__ slots, float* __restrict__ wts)
{
  const int token = blockIdx.x;
  const int lane  = threadIdx.x;
  const float* xr = x + (size_t)token * D_MODEL;

  float xv[16];
  #pragma unroll
  for (int j = 0; j < 16; ++j) xv[j] = xr[j * 64 + lane];

  float logit[N_EXP];
  #pragma unroll
  for (int e = 0; e < N_EXP; ++e) {
    const float* w = wr + e * D_MODEL;
    float p = 0.f;
    #pragma unroll
    for (int j = 0; j < 16; ++j) p += xv[j] * w[j * 64 + lane];
    #pragma unroll
    for (int o = 32; o > 0; o >>= 1) p += __shfl_xor(p, o, 64);
    logit[e] = p;
  }

  if (lane == 0) {
    float v0 = -1e30f, v1 = -1e30f; int i0 = 0, i1 = 0;
    #pragma unroll
    for (int e = 0; e < N_EXP; ++e) {
      float v = logit[e];
      if (v > v0)      { v1 = v0; i1 = i0; v0 = v; i0 = e; }
      else if (v > v1) { v1 = v; i1 = e; }
    }
    float t  = expf(v1 - v0);
    float w0 = 1.f / (1.f + t);
    float w1 = t   / (1.f + t);
    int p0 = atomicAdd(&counts[i0], 1);
    tok_list[i0 * LISTCAP + p0] = token;
    int p1 = atomicAdd(&counts[i1], 1);
    tok_list[i1 * LISTCAP + p1] = token;
    slots[token * 2]     = i0 * LISTCAP + p0;
    slots[token * 2 + 1] = i1 * LISTCAP + p1;
    wts[token * 2]     = w0;
    wts[token * 2 + 1] = w1;
  }
}

// Gather x rows into expert-sorted contiguous Xg (bf16).
__global__ __launch_bounds__(256) void gather_kernel(
    const float* __restrict__ x, const int* __restrict__ counts,
    const int* __restrict__ offsets, const int* __restrict__ tok_list,
    ushort* __restrict__ Xg)
{
  const int e  = blockIdx.y;
  const int Ne = counts[e];
  const int i0 = blockIdx.x * 4;
  if (i0 >= Ne) return;
  const int t = threadIdx.x;
  const int i = i0 + (t >> 6);
  if (i >= Ne) return;
  const int lane = t & 63;
  const int tok  = tok_list[e * LISTCAP + i];
  const float* src = x + (size_t)tok * D_MODEL + lane * 16;
  ushort* dst = Xg + (size_t)(offsets[e] + i) * D_MODEL + lane * 16;
  #pragma unroll
  for (int j = 0; j < 2; ++j) {
    float4 a = *(const float4*)(src + j * 8);
    float4 b = *(const float4*)(src + j * 8 + 4);
    ushort u8[8] = {f2bf(a.x), f2bf(a.y), f2bf(a.z), f2bf(a.w),
                    f2bf(b.x), f2bf(b.y), f2bf(b.z), f2bf(b.w)};
    *(uint4*)(dst + j * 8) = *(uint4*)u8;
  }
}

// fp32 -> bf16 weight conversion. grid 8192 x 256, 8 elems/thread = 16.78M elems.
__global__ __launch_bounds__(256) void convert_kernel(
    const float* __restrict__ src, ushort* __restrict__ dst)
{
  const size_t base = ((size_t)blockIdx.x * 256 + threadIdx.x) * 8;
  float4 a = *(const float4*)(src + base);
  float4 b = *(const float4*)(src + base + 4);
  ushort u8[8] = {f2bf(a.x), f2bf(a.y), f2bf(a.z), f2bf(a.w),
                  f2bf(b.x), f2bf(b.y), f2bf(b.z), f2bf(b.w)};
  *(uint4*)(dst + base) = *(uint4*)u8;
}

// Gate+Up grouped GEMM + SwiGLU -> H (bf16).
// 128x128 tile, BK=64, 4 waves, global_load_lds(16B) + XOR swizzle:
//   LDS[r][c16] holds global[r][c16 ^ (r&7)]  (16B chunks, 8 per 64-short row)
__global__ __launch_bounds__(256, 2) void gateup2_kernel(
    const ushort* __restrict__ Xg, const ushort* __restrict__ WgB,
    const ushort* __restrict__ WuB, const int* __restrict__ counts,
    const int* __restrict__ offsets, ushort* __restrict__ H)
{
  const int e  = blockIdx.z;
  const int Ne = counts[e];
  const int m0 = blockIdx.y * 128;
  if (m0 >= Ne) return;
  const int n0 = blockIdx.x * 128;

  __shared__ ushort As[128 * 64];
  __shared__ ushort Bg[128 * 64];
  __shared__ ushort Bu[128 * 64];

  const int tid  = threadIdx.x;
  const int wave = tid >> 6;
  const int lane = tid & 63;
  const int rowbase = offsets[e] + m0;

  // staging pointers: lane covers row (wave*32 + i*8 + lane>>3), chunk lane&7
  const int rsub = lane >> 3;
  const int cchk = lane & 7;
  const ushort* aSrc[4]; const ushort* gSrc[4]; const ushort* uSrc[4];
  ushort *aDst[4], *gDst[4], *uDst[4];
  #pragma unroll
  for (int i = 0; i < 4; ++i) {
    int r  = wave * 32 + i * 8 + rsub;
    int co = (cchk ^ (r & 7)) << 3;
    aSrc[i] = Xg  + (size_t)(rowbase + r) * D_MODEL + co;
    int rb  = e * D_FFN + n0 + r;
    gSrc[i] = WgB + (size_t)rb * D_MODEL + co;
    uSrc[i] = WuB + (size_t)rb * D_MODEL + co;
    aDst[i] = &As[(wave * 32 + i * 8) * 64];
    gDst[i] = &Bg[(wave * 32 + i * 8) * 64];
    uDst[i] = &Bu[(wave * 32 + i * 8) * 64];
  }

  const int wm = (wave >> 1) * 64;
  const int wn = (wave & 1) * 64;
  const int lrow = lane & 15;
  const int lq   = lane >> 4;

  f32x4 accg[4][4], accu[4][4];
  #pragma unroll
  for (int i = 0; i < 4; ++i)
    #pragma unroll
    for (int j = 0; j < 4; ++j) {
      accg[i][j] = f32x4{0.f, 0.f, 0.f, 0.f};
      accu[i][j] = f32x4{0.f, 0.f, 0.f, 0.f};
    }

  for (int k0 = 0; k0 < D_MODEL; k0 += 64) {
    #pragma unroll
    for (int i = 0; i < 4; ++i) {
      gl2lds16(aSrc[i], aDst[i]);
      gl2lds16(gSrc[i], gDst[i]);
      gl2lds16(uSrc[i], uDst[i]);
      aSrc[i] += 64; gSrc[i] += 64; uSrc[i] += 64;
    }
    __syncthreads();

    #pragma unroll
    for (int kk = 0; kk < 2; ++kk) {
      const int c = kk * 4 + lq;             // 16B chunk 0..7
      bf16x8 af[4], bgf[4], buf[4];
      #pragma unroll
      for (int mi = 0; mi < 4; ++mi) {
        int r = wm + mi * 16 + lrow;
        af[mi] = *(const bf16x8*)&As[r * 64 + ((c ^ (r & 7)) << 3)];
      }
      #pragma unroll
      for (int ni = 0; ni < 4; ++ni) {
        int r = wn + ni * 16 + lrow;
        int off = r * 64 + ((c ^ (r & 7)) << 3);
        bgf[ni] = *(const bf16x8*)&Bg[off];
        buf[ni] = *(const bf16x8*)&Bu[off];
      }
      #pragma unroll
      for (int mi = 0; mi < 4; ++mi)
        #pragma unroll
        for (int ni = 0; ni < 4; ++ni) {
          accg[mi][ni] = __builtin_amdgcn_mfma_f32_16x16x32_bf16(af[mi], bgf[ni], accg[mi][ni], 0, 0, 0);
          accu[mi][ni] = __builtin_amdgcn_mfma_f32_16x16x32_bf16(af[mi], buf[ni], accu[mi][ni], 0, 0, 0);
        }
    }
    __syncthreads();
  }

  #pragma unroll
  for (int mi = 0; mi < 4; ++mi)
    #pragma unroll
    for (int r4 = 0; r4 < 4; ++r4) {
      int m = wm + mi * 16 + lq * 4 + r4;
      if (m0 + m < Ne) {
        ushort* hr = H + (size_t)(rowbase + m) * D_FFN + n0 + wn + lrow;
        #pragma unroll
        for (int ni = 0; ni < 4; ++ni) {
          float g = accg[mi][ni][r4];
          float u = accu[mi][ni][r4];
          float h = g / (1.f + __expf(-g)) * u;
          hr[ni * 16] = f2bf(h);
        }
      }
    }
}

// Down grouped GEMM -> Y rows (bf16, unweighted).
__global__ __launch_bounds__(256, 2) void down2_kernel(
    const ushort* __restrict__ H, const ushort* __restrict__ WdB,
    const int* __restrict__ counts, const int* __restrict__ offsets,
    ushort* __restrict__ Y)
{
  const int e  = blockIdx.z;
  const int Ne = counts[e];
  const int m0 = blockIdx.y * 128;
  if (m0 >= Ne) return;
  const int n0 = blockIdx.x * 128;

  __shared__ ushort As[128 * 64];
  __shared__ ushort Bd[128 * 64];

  const int tid  = threadIdx.x;
  const int wave = tid >> 6;
  const int lane = tid & 63;
  const int rowbase = offsets[e] + m0;

  const int rsub = lane >> 3;
  const int cchk = lane & 7;
  const ushort* aSrc[4]; const ushort* bSrc[4];
  ushort *aDst[4], *bDst[4];
  #pragma unroll
  for (int i = 0; i < 4; ++i) {
    int r  = wave * 32 + i * 8 + rsub;
    int co = (cchk ^ (r & 7)) << 3;
    aSrc[i] = H   + (size_t)(rowbase + r) * D_FFN + co;
    bSrc[i] = WdB + (size_t)(e * D_MODEL + n0 + r) * D_FFN + co;
    aDst[i] = &As[(wave * 32 + i * 8) * 64];
    bDst[i] = &Bd[(wave * 32 + i * 8) * 64];
  }

  const int wm = (wave >> 1) * 64;
  const int wn = (wave & 1) * 64;
  const int lrow = lane & 15;
  const int lq   = lane >> 4;

  f32x4 acc[4][4];
  #pragma unroll
  for (int i = 0; i < 4; ++i)
    #pragma unroll
    for (int j = 0; j < 4; ++j) acc[i][j] = f32x4{0.f, 0.f, 0.f, 0.f};

  for (int k0 = 0; k0 < D_FFN; k0 += 64) {
    #pragma unroll
    for (int i = 0; i < 4; ++i) {
      gl2lds16(aSrc[i], aDst[i]);
      gl2lds16(bSrc[i], bDst[i]);
      aSrc[i] += 64; bSrc[i] += 64;
    }
    __syncthreads();

    #pragma unroll
    for (int kk = 0; kk < 2; ++kk) {
      const int c = kk * 4 + lq;
      bf16x8 af[4], bf[4];
      #pragma unroll
      for (int mi = 0; mi < 4; ++mi) {
        int r = wm + mi * 16 + lrow;
        af[mi] = *(const bf16x8*)&As[r * 64 + ((c ^ (r & 7)) << 3)];
      }
      #pragma unroll
      for (int ni = 0; ni < 4; ++ni) {
        int r = wn + ni * 16 + lrow;
        bf[ni] = *(const bf16x8*)&Bd[r * 64 + ((c ^ (r & 7)) << 3)];
      }
      #pragma unroll
      for (int mi = 0; mi < 4; ++mi)
        #pragma unroll
        for (int ni = 0; ni < 4; ++ni)
          acc[mi][ni] = __builtin_amdgcn_mfma_f32_16x16x32_bf16(af[mi], bf[ni], acc[mi][ni], 0, 0, 0);
    }
    __syncthreads();
  }

  #pragma unroll
  for (int mi = 0; mi < 4; ++mi)
    #pragma unroll
    for (int r4 = 0; r4 < 4; ++r4) {
      int m = wm + mi * 16 + lq * 4 + r4;
      if (m0 + m < Ne) {
        ushort* yr = Y + (size_t)(rowbase + m) * D_MODEL + n0 + wn + lrow;
        #pragma unroll
        for (int ni = 0; ni < 4; ++ni)
          yr[ni * 16] = f2bf(acc[mi][ni][r4]);
      }
    }
}

// Combine the 2 expert rows per token + LayerNorm -> out (fp32).
__global__ __launch_bounds__(256) void combine_ln_kernel(
    const ushort* __restrict__ Y, const int* __restrict__ slots,
    const float* __restrict__ wts, const int* __restrict__ offsets,
    const float* __restrict__ gamma, const float* __restrict__ beta,
    float* __restrict__ out)
{
  const int token = blockIdx.x;
  const int t = threadIdx.x;
  const int s0 = slots[token * 2], s1 = slots[token * 2 + 1];
  const float w0 = wts[token * 2], w1 = wts[token * 2 + 1];
  const int r0 = offsets[s0 >> 12] + (s0 & (LISTCAP - 1));
  const int r1 = offsets[s1 >> 12] + (s1 & (LISTCAP - 1));

  ushort4 a = *(const ushort4*)(Y + (size_t)r0 * D_MODEL + t * 4);
  ushort4 b = *(const ushort4*)(Y + (size_t)r1 * D_MODEL + t * 4);
  float4 v;
  v.x = w0 * bf2f(a.x) + w1 * bf2f(b.x);
  v.y = w0 * bf2f(a.y) + w1 * bf2f(b.y);
  v.z = w0 * bf2f(a.z) + w1 * bf2f(b.z);
  v.w = w0 * bf2f(a.w) + w1 * bf2f(b.w);

  float s = v.x + v.y + v.z + v.w;
  #pragma unroll
  for (int o = 32; o > 0; o >>= 1) s += __shfl_xor(s, o, 64);
  __shared__ float red[4];
  const int wave = t >> 6, lane = t & 63;
  if (lane == 0) red[wave] = s;
  __syncthreads();
  float mean = (red[0] + red[1] + red[2] + red[3]) * (1.f / D_MODEL);

  float dx = v.x - mean, dy = v.y - mean, dz = v.z - mean, dw = v.w - mean;
  float ss = dx * dx + dy * dy + dz * dz + dw * dw;
  #pragma unroll
  for (int o = 32; o > 0; o >>= 1) ss += __shfl_xor(ss, o, 64);
  __syncthreads();
  if (lane == 0) red[wave] = ss;
  __syncthreads();
  float var = (red[0] + red[1] + red[2] + red[3]) * (1.f / D_MODEL);
  float rs  = rsqrtf(var + 1e-5f);

  float4 g = ((const float4*)gamma)[t];
  float4 bb = ((const float4*)beta)[t];
  float4 o4;
  o4.x = dx * rs * g.x + bb.x;
  o4.y = dy * rs * g.y + bb.y;
  o4.z = dz * rs * g.z + bb.z;
  o4.w = dw * rs * g.w + bb.w;
  ((float4*)(out + (size_t)token * D_MODEL))[t] = o4;
}

// ======================= FALLBACK (round-1, known-correct) ==================
__global__ __launch_bounds__(64) void router_kernel(
    const float* __restrict__ x, const float* __restrict__ wr,
    ushort* __restrict__ xb, int* __restrict__ counts,
    int* __restrict__ tok_list, float* __restrict__ wt_list)
{
  const int token = blockIdx.x;
  const int lane  = threadIdx.x;
  const float* xr = x + (size_t)token * D_MODEL;
  float xv[16];
  #pragma unroll
  for (int j = 0; j < 16; ++j) xv[j] = xr[j * 64 + lane];
  ushort* xbr = xb + (size_t)token * D_MODEL;
  #pragma unroll
  for (int j = 0; j < 16; ++j) xbr[j * 64 + lane] = f2bf(xv[j]);
  float logit[N_EXP];
  #pragma unroll
  for (int e = 0; e < N_EXP; ++e) {
    const float* w = wr + e * D_MODEL;
    float p = 0.f;
    #pragma unroll
    for (int j = 0; j < 16; ++j) p += xv[j] * w[j * 64 + lane];
    #pragma unroll
    for (int o = 32; o > 0; o >>= 1) p += __shfl_xor(p, o, 64);
    logit[e] = p;
  }
  if (lane == 0) {
    float v0 = -1e30f, v1 = -1e30f; int i0 = 0, i1 = 0;
    #pragma unroll
    for (int e = 0; e < N_EXP; ++e) {
      float v = logit[e];
      if (v > v0)      { v1 = v0; i1 = i0; v0 = v; i0 = e; }
      else if (v > v1) { v1 = v; i1 = e; }
    }
    float t  = expf(v1 - v0);
    float w0 = 1.f / (1.f + t);
    float w1 = t   / (1.f + t);
    int p0 = atomicAdd(&counts[i0], 1);
    tok_list[i0 * LISTCAP + p0] = token;
    wt_list[i0 * LISTCAP + p0] = w0;
    int p1 = atomicAdd(&counts[i1], 1);
    tok_list[i1 * LISTCAP + p1] = token;
    wt_list[i1 * LISTCAP + p1] = w1;
  }
}

__global__ __launch_bounds__(256, 2) void gateup_kernel(
    const ushort* __restrict__ xb, const float* __restrict__ wg,
    const float* __restrict__ wu, const int* __restrict__ counts,
    const int* __restrict__ offsets, const int* __restrict__ tok_list,
    ushort* __restrict__ H)
{
  const int e  = blockIdx.z;
  const int Ne = counts[e];
  const int m0 = blockIdx.y * 128;
  if (m0 >= Ne) return;
  const int n0 = blockIdx.x * 128;
  __shared__ ushort As[128][80];
  __shared__ ushort Bg[128][80];
  __shared__ ushort Bu[128][80];
  __shared__ int tok_s[128];
  const int tid = threadIdx.x;
  if (tid < 128) {
    int i = m0 + tid;
    tok_s[tid] = tok_list[e * LISTCAP + (i < Ne ? i : 0)];
  }
  __syncthreads();
  const int wave = tid >> 6;
  const int lane = tid & 63;
  const int wm   = (wave >> 1) * 64;
  const int wn   = (wave & 1) * 64;
  const int lrow = lane & 15;
  const int lk   = (lane >> 4) * 8;
  f32x4 accg[4][4], accu[4][4];
  #pragma unroll
  for (int i = 0; i < 4; ++i)
    #pragma unroll
    for (int j = 0; j < 4; ++j) {
      accg[i][j] = f32x4{0.f, 0.f, 0.f, 0.f};
      accu[i][j] = f32x4{0.f, 0.f, 0.f, 0.f};
    }
  const size_t wbase = ((size_t)e * D_FFN + n0) * D_MODEL;
  for (int k0 = 0; k0 < D_MODEL; k0 += 64) {
    #pragma unroll
    for (int r = 0; r < 4; ++r) {
      int idx = tid + r * 256;
      int row = idx >> 3;
      int c8  = (idx & 7) * 8;
      const ushort* src = xb + (size_t)tok_s[row] * D_MODEL + k0 + c8;
      *(uint4*)(&As[row][c8]) = *(const uint4*)src;
    }
    #pragma unroll
    for (int r = 0; r < 8; ++r) {
      int idx = tid + r * 256;
      int row = idx >> 4;
      int c4  = (idx & 15) * 4;
      const size_t off = wbase + (size_t)row * D_MODEL + k0 + c4;
      const float4 g = *(const float4*)(wg + off);
      const float4 u = *(const float4*)(wu + off);
      ushort4 gb; gb.x = f2bf(g.x); gb.y = f2bf(g.y); gb.z = f2bf(g.z); gb.w = f2bf(g.w);
      ushort4 ub; ub.x = f2bf(u.x); ub.y = f2bf(u.y); ub.z = f2bf(u.z); ub.w = f2bf(u.w);
      *(ushort4*)(&Bg[row][c4]) = gb;
      *(ushort4*)(&Bu[row][c4]) = ub;
    }
    __syncthreads();
    #pragma unroll
    for (int kk = 0; kk < 64; kk += 32) {
      bf16x8 af[4], bgf[4], buf[4];
      #pragma unroll
      for (int mi = 0; mi < 4; ++mi)
        af[mi] = *(const bf16x8*)(&As[wm + mi * 16 + lrow][kk + lk]);
      #pragma unroll
      for (int ni = 0; ni < 4; ++ni) {
        bgf[ni] = *(const bf16x8*)(&Bg[wn + ni * 16 + lrow][kk + lk]);
        buf[ni] = *(const bf16x8*)(&Bu[wn + ni * 16 + lrow][kk + lk]);
      }
      #pragma unroll
      for (int mi = 0; mi < 4; ++mi)
        #pragma unroll
        for (int ni = 0; ni < 4; ++ni) {
          accg[mi][ni] = __builtin_amdgcn_mfma_f32_16x16x32_bf16(af[mi], bgf[ni], accg[mi][ni], 0, 0, 0);
          accu[mi][ni] = __builtin_amdgcn_mfma_f32_16x16x32_bf16(af[mi], buf[ni], accu[mi][ni], 0, 0, 0);
        }
    }
    __syncthreads();
  }
  const int row_base = offsets[e] + m0;
  #pragma unroll
  for (int mi = 0; mi < 4; ++mi)
    #pragma unroll
    for (int ni = 0; ni < 4; ++ni)
      #pragma unroll
      for (int r4 = 0; r4 < 4; ++r4) {
        int m = wm + mi * 16 + (lane >> 4) * 4 + r4;
        if (m0 + m < Ne) {
          int n = wn + ni * 16 + (lane & 15);
          float g = accg[mi][ni][r4];
          float u = accu[mi][ni][r4];
          float h = g / (1.f + __expf(-g)) * u;
          H[(size_t)(row_base + m) * D_FFN + (n0 + n)] = f2bf(h);
        }
      }
}

__global__ __launch_bounds__(256, 2) void down_kernel(
    const ushort* __restrict__ H, const float* __restrict__ wd,
    const int* __restrict__ counts, const int* __restrict__ offsets,
    const int* __restrict__ tok_list, const float* __restrict__ wt_list,
    float* __restrict__ out)
{
  const int e  = blockIdx.z;
  const int Ne = counts[e];
  const int m0 = blockIdx.y * 128;
  if (m0 >= Ne) return;
  const int n0 = blockIdx.x * 128;
  __shared__ ushort As[128][80];
  __shared__ ushort Bd[128][80];
  __shared__ int   tok_s[128];
  __shared__ float wt_s[128];
  const int tid = threadIdx.x;
  if (tid < 128) {
    int i  = m0 + tid;
    int ok = (i < Ne);
    tok_s[tid] = tok_list[e * LISTCAP + (ok ? i : 0)];
    wt_s[tid]  = ok ? wt_list[e * LISTCAP + i] : 0.f;
  }
  __syncthreads();
  const int wave = tid >> 6;
  const int lane = tid & 63;
  const int wm   = (wave >> 1) * 64;
  const int wn   = (wave & 1) * 64;
  const int lrow = lane & 15;
  const int lk   = (lane >> 4) * 8;
  const int row_base = offsets[e] + m0;
  f32x4 acc[4][4];
  #pragma unroll
  for (int i = 0; i < 4; ++i)
    #pragma unroll
    for (int j = 0; j < 4; ++j) acc[i][j] = f32x4{0.f, 0.f, 0.f, 0.f};
  const size_t wdbase = ((size_t)e * D_MODEL + n0) * D_FFN;
  for (int k0 = 0; k0 < D_FFN; k0 += 64) {
    #pragma unroll
    for (int r = 0; r < 4; ++r) {
      int idx = tid + r * 256;
      int row = idx >> 3;
      int c8  = (idx & 7) * 8;
      const ushort* src = H + (size_t)(row_base + row) * D_FFN + k0 + c8;
      *(uint4*)(&As[row][c8]) = *(const uint4*)src;
    }
    #pragma unroll
    for (int r = 0; r < 8; ++r) {
      int idx = tid + r * 256;
      int row = idx >> 4;
      int c4  = (idx & 15) * 4;
      const float4 d = *(const float4*)(wd + wdbase + (size_t)row * D_FFN + k0 + c4);
      ushort4 db; db.x = f2bf(d.x); db.y = f2bf(d.y); db.z = f2bf(d.z); db.w = f2bf(d.w);
      *(ushort4*)(&Bd[row][c4]) = db;
    }
    __syncthreads();
    #pragma unroll
    for (int kk = 0; kk < 64; kk += 32) {
      bf16x8 af[4], bdf[4];
      #pragma unroll
      for (int mi = 0; mi < 4; ++mi)
        af[mi] = *(const bf16x8*)(&As[wm + mi * 16 + lrow][kk + lk]);
      #pragma unroll
      for (int ni = 0; ni < 4; ++ni)
        bdf[ni] = *(const bf16x8*)(&Bd[wn + ni * 16 + lrow][kk + lk]);
      #pragma unroll
      for (int mi = 0; mi < 4; ++mi)
        #pragma unroll
        for (int ni = 0; ni < 4; ++ni)
          acc[mi][ni] = __builtin_amdgcn_mfma_f32_16x16x32_bf16(af[mi], bdf[ni], acc[mi][ni], 0, 0, 0);
    }
    __syncthreads();
  }
  #pragma unroll
  for (int mi = 0; mi < 4; ++mi)
    #pragma unroll
    for (int ni = 0; ni < 4; ++ni)
      #pragma unroll
      for (int r4 = 0; r4 < 4; ++r4) {
        int m = wm + mi * 16 + (lane >> 4) * 4 + r4;
        if (m0 + m < Ne) {
          int n = wn + ni * 16 + (lane & 15);
          float v = acc[mi][ni][r4] * wt_s[m];
          atomicAdd(&out[(size_t)tok_s[m] * D_MODEL + (n0 + n)], v);
        }
      }
}

__global__ __launch_bounds__(256) void ln_kernel(
    float* __restrict__ out, const float* __restrict__ gamma,
    const float* __restrict__ beta)
{
  const int row = blockIdx.x;
  const int t   = threadIdx.x;
  float* rp = out + (size_t)row * D_MODEL;
  float4 v = ((const float4*)rp)[t];
  float s = v.x + v.y + v.z + v.w;
  #pragma unroll
  for (int o = 32; o > 0; o >>= 1) s += __shfl_xor(s, o, 64);
  __shared__ float red[4];
  const int wave = t >> 6, lane = t & 63;
  if (lane == 0) red[wave] = s;
  __syncthreads();
  float mean = (red[0] + red[1] + red[2] + red[3]) * (1.f / D_MODEL);
  float dx = v.x - mean, dy = v.y - mean, dz = v.z - mean, dw = v.w - mean;
  float ss = dx * dx + dy * dy + dz * dz + dw * dw;
  #pragma unroll
  for (int o = 32; o > 0; o >>= 1) ss += __shfl_xor(ss, o, 64);
  __syncthreads();
  if (lane == 0) red[wave] = ss;
  __syncthreads();
  float var = (red[0] + red[1] + red[2] + red[3]) * (1.f / D_MODEL);
  float rs  = rsqrtf(var + 1e-5f);
  float4 g = ((const float4*)gamma)[t];
  float4 b = ((const float4*)beta)[t];
  float4 o4;
  o4.x = dx * rs * g.x + b.x;
  o4.y = dy * rs * g.y + b.y;
  o4.z = dz * rs * g.z + b.z;
  o4.w = dw * rs * g.w + b.w;
  ((float4*)rp)[t] = o4;
}

// ======================= Launch =============================================
extern "C" void kernel_launch(void* const* d_in, const int* in_sizes, int n_in,
                              void* d_out, int out_size, void* d_ws, size_t ws_size,
                              hipStream_t stream) {
  const float* x        = (const float*)d_in[0];
  const float* w_router = (const float*)d_in[1];
  const float* w_gate   = (const float*)d_in[2];
  const float* w_up     = (const float*)d_in[3];
  const float* w_down   = (const float*)d_in[4];
  const float* ln_gamma = (const float*)d_in[5];
  const float* ln_beta  = (const float*)d_in[6];
  float* out = (float*)d_out;
  char* ws = (char*)d_ws;

  // fast-path workspace layout
  const size_t META   = 262144;
  const size_t W_ELEM = (size_t)N_EXP * D_FFN * D_MODEL;          // 16,777,216
  const size_t NEED   = META + 3 * W_ELEM * 2 + (size_t)ROWS_PAD * D_MODEL * 2
                        + (size_t)ROWS_PAD * D_FFN * 2;           // ~152 MB

  if (ws_size >= NEED) {
    int*   counts   = (int*)ws;
    int*   offsets  = (int*)(ws + 64);
    int*   tok_list = (int*)(ws + 4096);
    int*   slots    = (int*)(ws + 4096 + 131072);
    float* wts      = (float*)(ws + 4096 + 131072 + 32768);
    ushort* WgB = (ushort*)(ws + META);
    ushort* WuB = WgB + W_ELEM;
    ushort* WdB = WuB + W_ELEM;
    ushort* Xg  = WdB + W_ELEM;
    ushort* H   = Xg + (size_t)ROWS_PAD * D_MODEL;
    ushort* Y   = Xg;   // alias: Xg dead after gateup, Y written by down

    hipMemsetAsync(counts, 0, 64, stream);
    router2_kernel<<<TOKENS, 64, 0, stream>>>(x, w_router, counts, tok_list, slots, wts);
    prefix_kernel<<<1, 64, 0, stream>>>(counts, offsets);
    gather_kernel<<<dim3(1024, N_EXP), 256, 0, stream>>>(x, counts, offsets, tok_list, Xg);
    convert_kernel<<<8192, 256, 0, stream>>>(w_gate, WgB);
    convert_kernel<<<8192, 256, 0, stream>>>(w_up,  WuB);
    convert_kernel<<<8192, 256, 0, stream>>>(w_down, WdB);
    gateup2_kernel<<<dim3(D_FFN / 128, 32, N_EXP), 256, 0, stream>>>(
        Xg, WgB, WuB, counts, offsets, H);
    down2_kernel<<<dim3(D_MODEL / 128, 32, N_EXP), 256, 0, stream>>>(
        H, WdB, counts, offsets, Y);
    combine_ln_kernel<<<TOKENS, 256, 0, stream>>>(Y, slots, wts, offsets,
                                                  ln_gamma, ln_beta, out);
  } else {
    // round-1 fallback
    int*   counts   = (int*)ws;
    int*   offsets  = counts + 8;
    int*   tok_list = (int*)(ws + 256);
    float* wt_list  = (float*)(ws + 256 + LISTCAP * N_EXP * 4);
    ushort* xb      = (ushort*)(ws + 256 + LISTCAP * N_EXP * 8);
    ushort* H       = xb + (size_t)TOKENS * D_MODEL;

    hipMemsetAsync(counts, 0, 64, stream);
    hipMemsetAsync(out, 0, (size_t)TOKENS * D_MODEL * sizeof(float), stream);
    router_kernel<<<TOKENS, 64, 0, stream>>>(x, w_router, xb, counts, tok_list, wt_list);
    prefix_kernel<<<1, 64, 0, stream>>>(counts, offsets);
    gateup_kernel<<<dim3(D_FFN / 128, 32, N_EXP), 256, 0, stream>>>(
        xb, w_gate, w_up, counts, offsets, tok_list, H);
    down_kernel<<<dim3(D_MODEL / 128, 32, N_EXP), 256, 0, stream>>>(
        H, w_down, counts, offsets, tok_list, wt_list, out);
    ln_kernel<<<TOKENS, 256, 0, stream>>>(out, ln_gamma, ln_beta);
  }
}

// Round 3
// 458.046 us; speedup vs baseline: 1.7523x; 1.0974x over previous
//
#include <hip/hip_runtime.h>

// MoE layer: router top-2 + per-expert SwiGLU FFN + weighted combine + LayerNorm.
// Tokens=4096, D_MODEL=1024, D_FFN=2048, E=8, TOPK=2. fp32 I/O, bf16 MFMA inside.
//
// Round-3 fast path (6 dispatches):
//   memset(counts) -> router (logits+top2+xb bf16) -> convert3 (w{g,u,d}->bf16, fused)
//   -> gateup (128x64 tile, indirect-A global_load_lds, 3 blocks/CU) -> down -> combine+LN
// Fallback path (small ws): round-1 pipeline.

#define D_MODEL 1024
#define D_FFN   2048
#define N_EXP   8
#define TOKENS  4096
#define LISTCAP 4096
#define ROWS_PAD 8320
#define W_ELEM  16777216u   // N_EXP * D_FFN * D_MODEL

typedef __bf16 bf16x8 __attribute__((ext_vector_type(8)));
typedef float  f32x4  __attribute__((ext_vector_type(4)));

__device__ __forceinline__ ushort f2bf(float f) {
  union { float f; unsigned u; } v; v.f = f;
  unsigned u = v.u;
  u += 0x7fffu + ((u >> 16) & 1u);   // round-to-nearest-even
  return (ushort)(u >> 16);
}
__device__ __forceinline__ float bf2f(ushort h) {
  union { unsigned u; float f; } v; v.u = ((unsigned)h) << 16; return v.f;
}
__device__ __forceinline__ void gl2lds16(const ushort* g, ushort* l) {
  __builtin_amdgcn_global_load_lds(
      (const __attribute__((address_space(1))) unsigned int*)g,
      (__attribute__((address_space(3))) unsigned int*)l, 16, 0, 0);
}

// ======================= FAST PATH ==========================================

// Router: logits, top-2 softmax, expert lists, slots/weights, x -> xb (bf16).
// Lane owns 16 contiguous elements -> vectorized loads + 16B xb stores.
__global__ __launch_bounds__(64) void router3_kernel(
    const float* __restrict__ x, const float* __restrict__ wr,
    ushort* __restrict__ xb, int* __restrict__ counts,
    int* __restrict__ tok_list, int* __restrict__ slots, float* __restrict__ wts)
{
  const int token = blockIdx.x;
  const int lane  = threadIdx.x;
  const float* xr = x + (size_t)token * D_MODEL + lane * 16;

  float xv[16];
  #pragma unroll
  for (int j = 0; j < 16; ++j) xv[j] = xr[j];

  ushort* xbr = xb + (size_t)token * D_MODEL + lane * 16;
  #pragma unroll
  for (int half = 0; half < 2; ++half) {
    ushort u8[8];
    #pragma unroll
    for (int j = 0; j < 8; ++j) u8[j] = f2bf(xv[half * 8 + j]);
    *(uint4*)(xbr + half * 8) = *(uint4*)u8;
  }

  float logit[N_EXP];
  #pragma unroll
  for (int e = 0; e < N_EXP; ++e) {
    const float* w = wr + e * D_MODEL + lane * 16;
    float p = 0.f;
    #pragma unroll
    for (int j = 0; j < 16; ++j) p += xv[j] * w[j];
    #pragma unroll
    for (int o = 32; o > 0; o >>= 1) p += __shfl_xor(p, o, 64);
    logit[e] = p;
  }

  if (lane == 0) {
    float v0 = -1e30f, v1 = -1e30f; int i0 = 0, i1 = 0;
    #pragma unroll
    for (int e = 0; e < N_EXP; ++e) {
      float v = logit[e];
      if (v > v0)      { v1 = v0; i1 = i0; v0 = v; i0 = e; }
      else if (v > v1) { v1 = v; i1 = e; }
    }
    float t  = expf(v1 - v0);
    float w0 = 1.f / (1.f + t);
    float w1 = t   / (1.f + t);
    int p0 = atomicAdd(&counts[i0], 1);
    tok_list[i0 * LISTCAP + p0] = token;
    int p1 = atomicAdd(&counts[i1], 1);
    tok_list[i1 * LISTCAP + p1] = token;
    slots[token * 2]     = i0 * LISTCAP + p0;
    slots[token * 2 + 1] = i1 * LISTCAP + p1;
    wts[token * 2]     = w0;
    wts[token * 2 + 1] = w1;
  }
}

// Fused fp32 -> bf16 conversion of all three weight tensors (one dispatch).
__global__ __launch_bounds__(256) void convert3_kernel(
    const float* __restrict__ wg, const float* __restrict__ wu,
    const float* __restrict__ wd, ushort* __restrict__ dstBase)
{
  const int bid = blockIdx.x;
  const int arr = bid >> 13;              // 8192 blocks per array
  const float* src = (arr == 0) ? wg : (arr == 1) ? wu : wd;
  ushort* dst = dstBase + (size_t)arr * W_ELEM;
  const size_t base = (((size_t)(bid & 8191)) * 256 + threadIdx.x) * 8;
  float4 a = *(const float4*)(src + base);
  float4 b = *(const float4*)(src + base + 4);
  ushort u8[8] = {f2bf(a.x), f2bf(a.y), f2bf(a.z), f2bf(a.w),
                  f2bf(b.x), f2bf(b.y), f2bf(b.z), f2bf(b.w)};
  *(uint4*)(dst + base) = *(uint4*)u8;
}

// Gate+Up grouped GEMM + SwiGLU -> H (bf16).
// 128(M)x64(N) tile, BK=64, 4 waves (each 64x32 per matrix), indirect A via
// tok_list, global_load_lds(16B) + XOR swizzle: LDS[r][c16] = G[r][c16^(r&7)].
// acc = 64 AGPR, LDS = 32KB -> target 3 blocks/CU.
__global__ __launch_bounds__(256, 3) void gateup3_kernel(
    const ushort* __restrict__ xb, const ushort* __restrict__ WgB,
    const ushort* __restrict__ WuB, const int* __restrict__ counts,
    const int* __restrict__ tok_list, ushort* __restrict__ H)
{
  const int e  = blockIdx.z;
  const int Ne = counts[e];
  const int m0 = blockIdx.y * 128;
  if (m0 >= Ne) return;
  const int n0 = blockIdx.x * 64;

  int rowoff = 0;
  for (int j = 0; j < e; ++j) rowoff += counts[j];

  __shared__ ushort As[128 * 64];
  __shared__ ushort Bg[64 * 64];
  __shared__ ushort Bu[64 * 64];
  __shared__ int tok_s[128];

  const int tid = threadIdx.x;
  if (tid < 128) {
    int i = m0 + tid;
    tok_s[tid] = tok_list[e * LISTCAP + (i < Ne ? i : Ne - 1)];
  }
  __syncthreads();

  const int wave = tid >> 6;
  const int lane = tid & 63;
  const int rsub = lane >> 3;
  const int cchk = lane & 7;
  const int co   = (cchk ^ rsub) << 3;    // r&7 == rsub for all staged rows

  const ushort* aSrc[4];
  #pragma unroll
  for (int i = 0; i < 4; ++i)
    aSrc[i] = xb + (size_t)tok_s[wave * 32 + i * 8 + rsub] * D_MODEL + co;
  const ushort* gS = WgB + ((size_t)e * D_FFN + n0 + wave * 16 + rsub) * D_MODEL + co;
  const ushort* uS = WuB + ((size_t)e * D_FFN + n0 + wave * 16 + rsub) * D_MODEL + co;
  ushort* aD = &As[(wave * 32) * 64];
  ushort* gD = &Bg[(wave * 16) * 64];
  ushort* uD = &Bu[(wave * 16) * 64];

  const int wm   = (wave >> 1) * 64;
  const int wn   = (wave & 1) * 32;
  const int lrow = lane & 15;
  const int lq   = lane >> 4;

  f32x4 accg[4][2], accu[4][2];
  #pragma unroll
  for (int i = 0; i < 4; ++i)
    #pragma unroll
    for (int j = 0; j < 2; ++j) {
      accg[i][j] = f32x4{0.f, 0.f, 0.f, 0.f};
      accu[i][j] = f32x4{0.f, 0.f, 0.f, 0.f};
    }

  for (int k0 = 0; k0 < D_MODEL; k0 += 64) {
    #pragma unroll
    for (int i = 0; i < 4; ++i) {
      gl2lds16(aSrc[i], aD + i * 8 * 64);
      aSrc[i] += 64;
    }
    #pragma unroll
    for (int i = 0; i < 2; ++i) {
      gl2lds16(gS + (size_t)i * 8 * D_MODEL, gD + i * 8 * 64);
      gl2lds16(uS + (size_t)i * 8 * D_MODEL, uD + i * 8 * 64);
    }
    gS += 64; uS += 64;
    __syncthreads();

    #pragma unroll
    for (int kk = 0; kk < 2; ++kk) {
      const int c = kk * 4 + lq;
      bf16x8 af[4], bgf[2], buf[2];
      #pragma unroll
      for (int mi = 0; mi < 4; ++mi) {
        int r = wm + mi * 16 + lrow;
        af[mi] = *(const bf16x8*)&As[r * 64 + ((c ^ (r & 7)) << 3)];
      }
      #pragma unroll
      for (int ni = 0; ni < 2; ++ni) {
        int r = wn + ni * 16 + lrow;
        int off = r * 64 + ((c ^ (r & 7)) << 3);
        bgf[ni] = *(const bf16x8*)&Bg[off];
        buf[ni] = *(const bf16x8*)&Bu[off];
      }
      #pragma unroll
      for (int mi = 0; mi < 4; ++mi)
        #pragma unroll
        for (int ni = 0; ni < 2; ++ni) {
          accg[mi][ni] = __builtin_amdgcn_mfma_f32_16x16x32_bf16(af[mi], bgf[ni], accg[mi][ni], 0, 0, 0);
          accu[mi][ni] = __builtin_amdgcn_mfma_f32_16x16x32_bf16(af[mi], buf[ni], accu[mi][ni], 0, 0, 0);
        }
    }
    __syncthreads();
  }

  const int rowbase = rowoff + m0;
  #pragma unroll
  for (int mi = 0; mi < 4; ++mi)
    #pragma unroll
    for (int r4 = 0; r4 < 4; ++r4) {
      int m = wm + mi * 16 + lq * 4 + r4;
      if (m0 + m < Ne) {
        ushort* hr = H + (size_t)(rowbase + m) * D_FFN + n0 + wn + lrow;
        #pragma unroll
        for (int ni = 0; ni < 2; ++ni) {
          float g = accg[mi][ni][r4];
          float u = accu[mi][ni][r4];
          float h = g / (1.f + __expf(-g)) * u;
          hr[ni * 16] = f2bf(h);
        }
      }
    }
}

// Down grouped GEMM -> Y rows (bf16, unweighted). 128x128 tile, BK=64.
__global__ __launch_bounds__(256, 3) void down3_kernel(
    const ushort* __restrict__ H, const ushort* __restrict__ WdB,
    const int* __restrict__ counts, ushort* __restrict__ Y)
{
  const int e  = blockIdx.z;
  const int Ne = counts[e];
  const int m0 = blockIdx.y * 128;
  if (m0 >= Ne) return;
  const int n0 = blockIdx.x * 128;

  int rowoff = 0;
  for (int j = 0; j < e; ++j) rowoff += counts[j];
  const int rowbase = rowoff + m0;

  __shared__ ushort As[128 * 64];
  __shared__ ushort Bd[128 * 64];

  const int tid  = threadIdx.x;
  const int wave = tid >> 6;
  const int lane = tid & 63;
  const int rsub = lane >> 3;
  const int cchk = lane & 7;
  const int co   = (cchk ^ rsub) << 3;

  const ushort* aS = H   + (size_t)(rowbase + wave * 32 + rsub) * D_FFN + co;
  const ushort* bS = WdB + (size_t)(e * D_MODEL + n0 + wave * 32 + rsub) * D_FFN + co;
  ushort* aD = &As[(wave * 32) * 64];
  ushort* bD = &Bd[(wave * 32) * 64];

  const int wm   = (wave >> 1) * 64;
  const int wn   = (wave & 1) * 64;
  const int lrow = lane & 15;
  const int lq   = lane >> 4;

  f32x4 acc[4][4];
  #pragma unroll
  for (int i = 0; i < 4; ++i)
    #pragma unroll
    for (int j = 0; j < 4; ++j) acc[i][j] = f32x4{0.f, 0.f, 0.f, 0.f};

  for (int k0 = 0; k0 < D_FFN; k0 += 64) {
    #pragma unroll
    for (int i = 0; i < 4; ++i) {
      gl2lds16(aS + (size_t)i * 8 * D_FFN, aD + i * 8 * 64);
      gl2lds16(bS + (size_t)i * 8 * D_FFN, bD + i * 8 * 64);
    }
    aS += 64; bS += 64;
    __syncthreads();

    #pragma unroll
    for (int kk = 0; kk < 2; ++kk) {
      const int c = kk * 4 + lq;
      bf16x8 af[4], bf[4];
      #pragma unroll
      for (int mi = 0; mi < 4; ++mi) {
        int r = wm + mi * 16 + lrow;
        af[mi] = *(const bf16x8*)&As[r * 64 + ((c ^ (r & 7)) << 3)];
      }
      #pragma unroll
      for (int ni = 0; ni < 4; ++ni) {
        int r = wn + ni * 16 + lrow;
        bf[ni] = *(const bf16x8*)&Bd[r * 64 + ((c ^ (r & 7)) << 3)];
      }
      #pragma unroll
      for (int mi = 0; mi < 4; ++mi)
        #pragma unroll
        for (int ni = 0; ni < 4; ++ni)
          acc[mi][ni] = __builtin_amdgcn_mfma_f32_16x16x32_bf16(af[mi], bf[ni], acc[mi][ni], 0, 0, 0);
    }
    __syncthreads();
  }

  #pragma unroll
  for (int mi = 0; mi < 4; ++mi)
    #pragma unroll
    for (int r4 = 0; r4 < 4; ++r4) {
      int m = wm + mi * 16 + lq * 4 + r4;
      if (m0 + m < Ne) {
        ushort* yr = Y + (size_t)(rowbase + m) * D_MODEL + n0 + wn + lrow;
        #pragma unroll
        for (int ni = 0; ni < 4; ++ni)
          yr[ni * 16] = f2bf(acc[mi][ni][r4]);
      }
    }
}

// Combine the 2 expert rows per token + LayerNorm -> out (fp32).
__global__ __launch_bounds__(256) void combine_ln3_kernel(
    const ushort* __restrict__ Y, const int* __restrict__ slots,
    const float* __restrict__ wts, const int* __restrict__ counts,
    const float* __restrict__ gamma, const float* __restrict__ beta,
    float* __restrict__ out)
{
  const int token = blockIdx.x;
  const int t = threadIdx.x;

  __shared__ int offs_s[N_EXP];
  if (t == 0) {
    int s = 0;
    #pragma unroll
    for (int j = 0; j < N_EXP; ++j) { offs_s[j] = s; s += counts[j]; }
  }
  __syncthreads();

  const int s0 = slots[token * 2], s1 = slots[token * 2 + 1];
  const float w0 = wts[token * 2], w1 = wts[token * 2 + 1];
  const int r0 = offs_s[s0 >> 12] + (s0 & (LISTCAP - 1));
  const int r1 = offs_s[s1 >> 12] + (s1 & (LISTCAP - 1));

  ushort4 a = *(const ushort4*)(Y + (size_t)r0 * D_MODEL + t * 4);
  ushort4 b = *(const ushort4*)(Y + (size_t)r1 * D_MODEL + t * 4);
  float4 v;
  v.x = w0 * bf2f(a.x) + w1 * bf2f(b.x);
  v.y = w0 * bf2f(a.y) + w1 * bf2f(b.y);
  v.z = w0 * bf2f(a.z) + w1 * bf2f(b.z);
  v.w = w0 * bf2f(a.w) + w1 * bf2f(b.w);

  float s = v.x + v.y + v.z + v.w;
  #pragma unroll
  for (int o = 32; o > 0; o >>= 1) s += __shfl_xor(s, o, 64);
  __shared__ float red[4];
  const int wave = t >> 6, lane = t & 63;
  if (lane == 0) red[wave] = s;
  __syncthreads();
  float mean = (red[0] + red[1] + red[2] + red[3]) * (1.f / D_MODEL);

  float dx = v.x - mean, dy = v.y - mean, dz = v.z - mean, dw = v.w - mean;
  float ss = dx * dx + dy * dy + dz * dz + dw * dw;
  #pragma unroll
  for (int o = 32; o > 0; o >>= 1) ss += __shfl_xor(ss, o, 64);
  __syncthreads();
  if (lane == 0) red[wave] = ss;
  __syncthreads();
  float var = (red[0] + red[1] + red[2] + red[3]) * (1.f / D_MODEL);
  float rs  = rsqrtf(var + 1e-5f);

  float4 g = ((const float4*)gamma)[t];
  float4 bb = ((const float4*)beta)[t];
  float4 o4;
  o4.x = dx * rs * g.x + bb.x;
  o4.y = dy * rs * g.y + bb.y;
  o4.z = dz * rs * g.z + bb.z;
  o4.w = dw * rs * g.w + bb.w;
  ((float4*)(out + (size_t)token * D_MODEL))[t] = o4;
}

// ======================= FALLBACK (round-1, known-correct) ==================
__global__ __launch_bounds__(64) void router_kernel(
    const float* __restrict__ x, const float* __restrict__ wr,
    ushort* __restrict__ xb, int* __restrict__ counts,
    int* __restrict__ tok_list, float* __restrict__ wt_list)
{
  const int token = blockIdx.x;
  const int lane  = threadIdx.x;
  const float* xr = x + (size_t)token * D_MODEL;
  float xv[16];
  #pragma unroll
  for (int j = 0; j < 16; ++j) xv[j] = xr[j * 64 + lane];
  ushort* xbr = xb + (size_t)token * D_MODEL;
  #pragma unroll
  for (int j = 0; j < 16; ++j) xbr[j * 64 + lane] = f2bf(xv[j]);
  float logit[N_EXP];
  #pragma unroll
  for (int e = 0; e < N_EXP; ++e) {
    const float* w = wr + e * D_MODEL;
    float p = 0.f;
    #pragma unroll
    for (int j = 0; j < 16; ++j) p += xv[j] * w[j * 64 + lane];
    #pragma unroll
    for (int o = 32; o > 0; o >>= 1) p += __shfl_xor(p, o, 64);
    logit[e] = p;
  }
  if (lane == 0) {
    float v0 = -1e30f, v1 = -1e30f; int i0 = 0, i1 = 0;
    #pragma unroll
    for (int e = 0; e < N_EXP; ++e) {
      float v = logit[e];
      if (v > v0)      { v1 = v0; i1 = i0; v0 = v; i0 = e; }
      else if (v > v1) { v1 = v; i1 = e; }
    }
    float t  = expf(v1 - v0);
    float w0 = 1.f / (1.f + t);
    float w1 = t   / (1.f + t);
    int p0 = atomicAdd(&counts[i0], 1);
    tok_list[i0 * LISTCAP + p0] = token;
    wt_list[i0 * LISTCAP + p0] = w0;
    int p1 = atomicAdd(&counts[i1], 1);
    tok_list[i1 * LISTCAP + p1] = token;
    wt_list[i1 * LISTCAP + p1] = w1;
  }
}

__global__ void prefix_kernel(const int* __restrict__ counts, int* __restrict__ offsets)
{
  if (threadIdx.x == 0 && blockIdx.x == 0) {
    int s = 0;
    for (int e = 0; e < N_EXP; ++e) { offsets[e] = s; s += counts[e]; }
  }
}

__global__ __launch_bounds__(256, 2) void gateup_kernel(
    const ushort* __restrict__ xb, const float* __restrict__ wg,
    const float* __restrict__ wu, const int* __restrict__ counts,
    const int* __restrict__ offsets, const int* __restrict__ tok_list,
    ushort* __restrict__ H)
{
  const int e  = blockIdx.z;
  const int Ne = counts[e];
  const int m0 = blockIdx.y * 128;
  if (m0 >= Ne) return;
  const int n0 = blockIdx.x * 128;
  __shared__ ushort As[128][80];
  __shared__ ushort Bg[128][80];
  __shared__ ushort Bu[128][80];
  __shared__ int tok_s[128];
  const int tid = threadIdx.x;
  if (tid < 128) {
    int i = m0 + tid;
    tok_s[tid] = tok_list[e * LISTCAP + (i < Ne ? i : 0)];
  }
  __syncthreads();
  const int wave = tid >> 6;
  const int lane = tid & 63;
  const int wm   = (wave >> 1) * 64;
  const int wn   = (wave & 1) * 64;
  const int lrow = lane & 15;
  const int lk   = (lane >> 4) * 8;
  f32x4 accg[4][4], accu[4][4];
  #pragma unroll
  for (int i = 0; i < 4; ++i)
    #pragma unroll
    for (int j = 0; j < 4; ++j) {
      accg[i][j] = f32x4{0.f, 0.f, 0.f, 0.f};
      accu[i][j] = f32x4{0.f, 0.f, 0.f, 0.f};
    }
  const size_t wbase = ((size_t)e * D_FFN + n0) * D_MODEL;
  for (int k0 = 0; k0 < D_MODEL; k0 += 64) {
    #pragma unroll
    for (int r = 0; r < 4; ++r) {
      int idx = tid + r * 256;
      int row = idx >> 3;
      int c8  = (idx & 7) * 8;
      const ushort* src = xb + (size_t)tok_s[row] * D_MODEL + k0 + c8;
      *(uint4*)(&As[row][c8]) = *(const uint4*)src;
    }
    #pragma unroll
    for (int r = 0; r < 8; ++r) {
      int idx = tid + r * 256;
      int row = idx >> 4;
      int c4  = (idx & 15) * 4;
      const size_t off = wbase + (size_t)row * D_MODEL + k0 + c4;
      const float4 g = *(const float4*)(wg + off);
      const float4 u = *(const float4*)(wu + off);
      ushort4 gb; gb.x = f2bf(g.x); gb.y = f2bf(g.y); gb.z = f2bf(g.z); gb.w = f2bf(g.w);
      ushort4 ub; ub.x = f2bf(u.x); ub.y = f2bf(u.y); ub.z = f2bf(u.z); ub.w = f2bf(u.w);
      *(ushort4*)(&Bg[row][c4]) = gb;
      *(ushort4*)(&Bu[row][c4]) = ub;
    }
    __syncthreads();
    #pragma unroll
    for (int kk = 0; kk < 64; kk += 32) {
      bf16x8 af[4], bgf[4], buf[4];
      #pragma unroll
      for (int mi = 0; mi < 4; ++mi)
        af[mi] = *(const bf16x8*)(&As[wm + mi * 16 + lrow][kk + lk]);
      #pragma unroll
      for (int ni = 0; ni < 4; ++ni) {
        bgf[ni] = *(const bf16x8*)(&Bg[wn + ni * 16 + lrow][kk + lk]);
        buf[ni] = *(const bf16x8*)(&Bu[wn + ni * 16 + lrow][kk + lk]);
      }
      #pragma unroll
      for (int mi = 0; mi < 4; ++mi)
        #pragma unroll
        for (int ni = 0; ni < 4; ++ni) {
          accg[mi][ni] = __builtin_amdgcn_mfma_f32_16x16x32_bf16(af[mi], bgf[ni], accg[mi][ni], 0, 0, 0);
          accu[mi][ni] = __builtin_amdgcn_mfma_f32_16x16x32_bf16(af[mi], buf[ni], accu[mi][ni], 0, 0, 0);
        }
    }
    __syncthreads();
  }
  const int row_base = offsets[e] + m0;
  #pragma unroll
  for (int mi = 0; mi < 4; ++mi)
    #pragma unroll
    for (int ni = 0; ni < 4; ++ni)
      #pragma unroll
      for (int r4 = 0; r4 < 4; ++r4) {
        int m = wm + mi * 16 + (lane >> 4) * 4 + r4;
        if (m0 + m < Ne) {
          int n = wn + ni * 16 + (lane & 15);
          float g = accg[mi][ni][r4];
          float u = accu[mi][ni][r4];
          float h = g / (1.f + __expf(-g)) * u;
          H[(size_t)(row_base + m) * D_FFN + (n0 + n)] = f2bf(h);
        }
      }
}

__global__ __launch_bounds__(256, 2) void down_kernel(
    const ushort* __restrict__ H, const float* __restrict__ wd,
    const int* __restrict__ counts, const int* __restrict__ offsets,
    const int* __restrict__ tok_list, const float* __restrict__ wt_list,
    float* __restrict__ out)
{
  const int e  = blockIdx.z;
  const int Ne = counts[e];
  const int m0 = blockIdx.y * 128;
  if (m0 >= Ne) return;
  const int n0 = blockIdx.x * 128;
  __shared__ ushort As[128][80];
  __shared__ ushort Bd[128][80];
  __shared__ int   tok_s[128];
  __shared__ float wt_s[128];
  const int tid = threadIdx.x;
  if (tid < 128) {
    int i  = m0 + tid;
    int ok = (i < Ne);
    tok_s[tid] = tok_list[e * LISTCAP + (ok ? i : 0)];
    wt_s[tid]  = ok ? wt_list[e * LISTCAP + i] : 0.f;
  }
  __syncthreads();
  const int wave = tid >> 6;
  const int lane = tid & 63;
  const int wm   = (wave >> 1) * 64;
  const int wn   = (wave & 1) * 64;
  const int lrow = lane & 15;
  const int lk   = (lane >> 4) * 8;
  const int row_base = offsets[e] + m0;
  f32x4 acc[4][4];
  #pragma unroll
  for (int i = 0; i < 4; ++i)
    #pragma unroll
    for (int j = 0; j < 4; ++j) acc[i][j] = f32x4{0.f, 0.f, 0.f, 0.f};
  const size_t wdbase = ((size_t)e * D_MODEL + n0) * D_FFN;
  for (int k0 = 0; k0 < D_FFN; k0 += 64) {
    #pragma unroll
    for (int r = 0; r < 4; ++r) {
      int idx = tid + r * 256;
      int row = idx >> 3;
      int c8  = (idx & 7) * 8;
      const ushort* src = H + (size_t)(row_base + row) * D_FFN + k0 + c8;
      *(uint4*)(&As[row][c8]) = *(const uint4*)src;
    }
    #pragma unroll
    for (int r = 0; r < 8; ++r) {
      int idx = tid + r * 256;
      int row = idx >> 4;
      int c4  = (idx & 15) * 4;
      const float4 d = *(const float4*)(wd + wdbase + (size_t)row * D_FFN + k0 + c4);
      ushort4 db; db.x = f2bf(d.x); db.y = f2bf(d.y); db.z = f2bf(d.z); db.w = f2bf(d.w);
      *(ushort4*)(&Bd[row][c4]) = db;
    }
    __syncthreads();
    #pragma unroll
    for (int kk = 0; kk < 64; kk += 32) {
      bf16x8 af[4], bdf[4];
      #pragma unroll
      for (int mi = 0; mi < 4; ++mi)
        af[mi] = *(const bf16x8*)(&As[wm + mi * 16 + lrow][kk + lk]);
      #pragma unroll
      for (int ni = 0; ni < 4; ++ni)
        bdf[ni] = *(const bf16x8*)(&Bd[wn + ni * 16 + lrow][kk + lk]);
      #pragma unroll
      for (int mi = 0; mi < 4; ++mi)
        #pragma unroll
        for (int ni = 0; ni < 4; ++ni)
          acc[mi][ni] = __builtin_amdgcn_mfma_f32_16x16x32_bf16(af[mi], bdf[ni], acc[mi][ni], 0, 0, 0);
    }
    __syncthreads();
  }
  #pragma unroll
  for (int mi = 0; mi < 4; ++mi)
    #pragma unroll
    for (int ni = 0; ni < 4; ++ni)
      #pragma unroll
      for (int r4 = 0; r4 < 4; ++r4) {
        int m = wm + mi * 16 + (lane >> 4) * 4 + r4;
        if (m0 + m < Ne) {
          int n = wn + ni * 16 + (lane & 15);
          float v = acc[mi][ni][r4] * wt_s[m];
          atomicAdd(&out[(size_t)tok_s[m] * D_MODEL + (n0 + n)], v);
        }
      }
}

__global__ __launch_bounds__(256) void ln_kernel(
    float* __restrict__ out, const float* __restrict__ gamma,
    const float* __restrict__ beta)
{
  const int row = blockIdx.x;
  const int t   = threadIdx.x;
  float* rp = out + (size_t)row * D_MODEL;
  float4 v = ((const float4*)rp)[t];
  float s = v.x + v.y + v.z + v.w;
  #pragma unroll
  for (int o = 32; o > 0; o >>= 1) s += __shfl_xor(s, o, 64);
  __shared__ float red[4];
  const int wave = t >> 6, lane = t & 63;
  if (lane == 0) red[wave] = s;
  __syncthreads();
  float mean = (red[0] + red[1] + red[2] + red[3]) * (1.f / D_MODEL);
  float dx = v.x - mean, dy = v.y - mean, dz = v.z - mean, dw = v.w - mean;
  float ss = dx * dx + dy * dy + dz * dz + dw * dw;
  #pragma unroll
  for (int o = 32; o > 0; o >>= 1) ss += __shfl_xor(ss, o, 64);
  __syncthreads();
  if (lane == 0) red[wave] = ss;
  __syncthreads();
  float var = (red[0] + red[1] + red[2] + red[3]) * (1.f / D_MODEL);
  float rs  = rsqrtf(var + 1e-5f);
  float4 g = ((const float4*)gamma)[t];
  float4 b = ((const float4*)beta)[t];
  float4 o4;
  o4.x = dx * rs * g.x + b.x;
  o4.y = dy * rs * g.y + b.y;
  o4.z = dz * rs * g.z + b.z;
  o4.w = dw * rs * g.w + b.w;
  ((float4*)rp)[t] = o4;
}

// ======================= Launch =============================================
extern "C" void kernel_launch(void* const* d_in, const int* in_sizes, int n_in,
                              void* d_out, int out_size, void* d_ws, size_t ws_size,
                              hipStream_t stream) {
  const float* x        = (const float*)d_in[0];
  const float* w_router = (const float*)d_in[1];
  const float* w_gate   = (const float*)d_in[2];
  const float* w_up     = (const float*)d_in[3];
  const float* w_down   = (const float*)d_in[4];
  const float* ln_gamma = (const float*)d_in[5];
  const float* ln_beta  = (const float*)d_in[6];
  float* out = (float*)d_out;
  char* ws = (char*)d_ws;

  const size_t META = 262144;
  const size_t NEED = META + 3 * (size_t)W_ELEM * 2
                      + (size_t)TOKENS * D_MODEL * 2
                      + (size_t)ROWS_PAD * D_FFN * 2;   // ~143.4 MB

  if (ws_size >= NEED) {
    int*   counts   = (int*)ws;
    int*   tok_list = (int*)(ws + 4096);
    int*   slots    = (int*)(ws + 4096 + 131072);
    float* wts      = (float*)(ws + 4096 + 131072 + 32768);
    ushort* WgB = (ushort*)(ws + META);
    ushort* WuB = WgB + W_ELEM;
    ushort* WdB = WuB + W_ELEM;
    ushort* xb  = WdB + W_ELEM;
    ushort* H   = xb + (size_t)TOKENS * D_MODEL;
    ushort* Y   = WgB;   // alias: WgB/WuB dead after gateup3

    hipMemsetAsync(counts, 0, 64, stream);
    router3_kernel<<<TOKENS, 64, 0, stream>>>(x, w_router, xb, counts, tok_list, slots, wts);
    convert3_kernel<<<3 * 8192, 256, 0, stream>>>(w_gate, w_up, w_down, WgB);
    gateup3_kernel<<<dim3(D_FFN / 64, 32, N_EXP), 256, 0, stream>>>(
        xb, WgB, WuB, counts, tok_list, H);
    down3_kernel<<<dim3(D_MODEL / 128, 32, N_EXP), 256, 0, stream>>>(
        H, WdB, counts, Y);
    combine_ln3_kernel<<<TOKENS, 256, 0, stream>>>(Y, slots, wts, counts,
                                                   ln_gamma, ln_beta, out);
  } else {
    // round-1 fallback
    int*   counts   = (int*)ws;
    int*   offsets  = counts + 8;
    int*   tok_list = (int*)(ws + 256);
    float* wt_list  = (float*)(ws + 256 + LISTCAP * N_EXP * 4);
    ushort* xb      = (ushort*)(ws + 256 + LISTCAP * N_EXP * 8);
    ushort* H       = xb + (size_t)TOKENS * D_MODEL;

    hipMemsetAsync(counts, 0, 64, stream);
    hipMemsetAsync(out, 0, (size_t)TOKENS * D_MODEL * sizeof(float), stream);
    router_kernel<<<TOKENS, 64, 0, stream>>>(x, w_router, xb, counts, tok_list, wt_list);
    prefix_kernel<<<1, 64, 0, stream>>>(counts, offsets);
    gateup_kernel<<<dim3(D_FFN / 128, 32, N_EXP), 256, 0, stream>>>(
        xb, w_gate, w_up, counts, offsets, tok_list, H);
    down_kernel<<<dim3(D_MODEL / 128, 32, N_EXP), 256, 0, stream>>>(
        H, w_down, counts, offsets, tok_list, wt_list, out);
    ln_kernel<<<TOKENS, 256, 0, stream>>>(out, ln_gamma, ln_beta);
  }
}

// Round 4
// 375.877 us; speedup vs baseline: 2.1353x; 1.2186x over previous
//
#include <hip/hip_runtime.h>

// MoE layer: router top-2 + per-expert SwiGLU FFN + weighted combine + LayerNorm.
// Tokens=4096, D_MODEL=1024, D_FFN=2048, E=8, TOPK=2. fp32 I/O, bf16 MFMA inside.
//
// Round-4 fast path (6 dispatches, zero global atomics):
//   router_a (logits+top2+xb, no atomics) -> build_lists (8 blocks, block-scan)
//   -> convert3 (w{g,u,d}->bf16) -> gateup3 (128x64) -> down3 (128x128) -> combine+LN
// Fallback path (small ws): round-1 pipeline.

#define D_MODEL 1024
#define D_FFN   2048
#define N_EXP   8
#define TOKENS  4096
#define LISTCAP 4096
#define ROWS_PAD 8320
#define W_ELEM  16777216u   // N_EXP * D_FFN * D_MODEL

typedef __bf16 bf16x8 __attribute__((ext_vector_type(8)));
typedef float  f32x4  __attribute__((ext_vector_type(4)));

__device__ __forceinline__ ushort f2bf(float f) {
  union { float f; unsigned u; } v; v.f = f;
  unsigned u = v.u;
  u += 0x7fffu + ((u >> 16) & 1u);   // round-to-nearest-even
  return (ushort)(u >> 16);
}
__device__ __forceinline__ float bf2f(ushort h) {
  union { unsigned u; float f; } v; v.u = ((unsigned)h) << 16; return v.f;
}
__device__ __forceinline__ void gl2lds16(const ushort* g, ushort* l) {
  __builtin_amdgcn_global_load_lds(
      (const __attribute__((address_space(1))) unsigned int*)g,
      (__attribute__((address_space(3))) unsigned int*)l, 16, 0, 0);
}

// ======================= FAST PATH ==========================================

// Phase A: per-token logits, top-2 softmax, x -> xb (bf16). NO atomics.
// 4 waves/block, one token per wave.
__global__ __launch_bounds__(256) void router_a_kernel(
    const float* __restrict__ x, const float* __restrict__ wr,
    ushort* __restrict__ xb, int* __restrict__ eids, float* __restrict__ wts)
{
  const int token = blockIdx.x * 4 + (threadIdx.x >> 6);
  const int lane  = threadIdx.x & 63;
  const float* xr = x + (size_t)token * D_MODEL + lane * 16;

  float xv[16];
  #pragma unroll
  for (int j = 0; j < 16; ++j) xv[j] = xr[j];

  ushort* xbr = xb + (size_t)token * D_MODEL + lane * 16;
  #pragma unroll
  for (int half = 0; half < 2; ++half) {
    ushort u8[8];
    #pragma unroll
    for (int j = 0; j < 8; ++j) u8[j] = f2bf(xv[half * 8 + j]);
    *(uint4*)(xbr + half * 8) = *(uint4*)u8;
  }

  float logit[N_EXP];
  #pragma unroll
  for (int e = 0; e < N_EXP; ++e) {
    const float* w = wr + e * D_MODEL + lane * 16;
    float p = 0.f;
    #pragma unroll
    for (int j = 0; j < 16; ++j) p += xv[j] * w[j];
    #pragma unroll
    for (int o = 32; o > 0; o >>= 1) p += __shfl_xor(p, o, 64);
    logit[e] = p;
  }

  if (lane == 0) {
    float v0 = -1e30f, v1 = -1e30f; int i0 = 0, i1 = 0;
    #pragma unroll
    for (int e = 0; e < N_EXP; ++e) {
      float v = logit[e];
      if (v > v0)      { v1 = v0; i1 = i0; v0 = v; i0 = e; }
      else if (v > v1) { v1 = v; i1 = e; }
    }
    float t  = expf(v1 - v0);           // stable 2-way softmax
    eids[token] = i0 | (i1 << 8);
    wts[token * 2]     = 1.f / (1.f + t);
    wts[token * 2 + 1] = t   / (1.f + t);
  }
}

// Phase B: one block per expert. Block-wide exclusive scan assigns positions.
// Deterministic, no atomics. Writes tok_list, slots, counts[e].
__global__ __launch_bounds__(1024) void build_lists_kernel(
    const int* __restrict__ eids, int* __restrict__ counts,
    int* __restrict__ tok_list, int* __restrict__ slots)
{
  const int e = blockIdx.x;
  const int t = threadIdx.x;

  int my_k[4];
  int c = 0;
  #pragma unroll
  for (int i = 0; i < 4; ++i) {
    int tok = t + i * 1024;
    int p  = eids[tok];
    int e0 = p & 0xff, e1 = (p >> 8) & 0xff;
    my_k[i] = (e0 == e) ? 0 : (e1 == e) ? 1 : -1;
    c += (my_k[i] >= 0) ? 1 : 0;
  }

  // wave-level inclusive scan of c
  const int wave = t >> 6, lane = t & 63;
  int v = c;
  #pragma unroll
  for (int o = 1; o < 64; o <<= 1) {
    int n = __shfl_up(v, o, 64);
    if (lane >= o) v += n;
  }

  __shared__ int wsum[16];
  __shared__ int wbase[16];
  if (lane == 63) wsum[wave] = v;
  __syncthreads();
  if (t == 0) {
    int s = 0;
    #pragma unroll
    for (int w = 0; w < 16; ++w) { wbase[w] = s; s += wsum[w]; }
    counts[e] = s;
  }
  __syncthreads();

  int pos = wbase[wave] + v - c;   // exclusive base for this thread
  #pragma unroll
  for (int i = 0; i < 4; ++i) {
    int tok = t + i * 1024;
    if (my_k[i] >= 0) {
      tok_list[e * LISTCAP + pos] = tok;
      slots[tok * 2 + my_k[i]] = e * LISTCAP + pos;
      pos++;
    }
  }
}

// Fused fp32 -> bf16 conversion of all three weight tensors (one dispatch).
__global__ __launch_bounds__(256) void convert3_kernel(
    const float* __restrict__ wg, const float* __restrict__ wu,
    const float* __restrict__ wd, ushort* __restrict__ dstBase)
{
  const int bid = blockIdx.x;
  const int arr = bid >> 13;              // 8192 blocks per array
  const float* src = (arr == 0) ? wg : (arr == 1) ? wu : wd;
  ushort* dst = dstBase + (size_t)arr * W_ELEM;
  const size_t base = (((size_t)(bid & 8191)) * 256 + threadIdx.x) * 8;
  float4 a = *(const float4*)(src + base);
  float4 b = *(const float4*)(src + base + 4);
  ushort u8[8] = {f2bf(a.x), f2bf(a.y), f2bf(a.z), f2bf(a.w),
                  f2bf(b.x), f2bf(b.y), f2bf(b.z), f2bf(b.w)};
  *(uint4*)(dst + base) = *(uint4*)u8;
}

// Gate+Up grouped GEMM + SwiGLU -> H (bf16).
// 128(M)x64(N) tile, BK=64, indirect A via tok_list, global_load_lds + XOR swizzle.
__global__ __launch_bounds__(256, 3) void gateup3_kernel(
    const ushort* __restrict__ xb, const ushort* __restrict__ WgB,
    const ushort* __restrict__ WuB, const int* __restrict__ counts,
    const int* __restrict__ tok_list, ushort* __restrict__ H)
{
  const int e  = blockIdx.z;
  const int Ne = counts[e];
  const int m0 = blockIdx.y * 128;
  if (m0 >= Ne) return;
  const int n0 = blockIdx.x * 64;

  int rowoff = 0;
  for (int j = 0; j < e; ++j) rowoff += counts[j];

  __shared__ ushort As[128 * 64];
  __shared__ ushort Bg[64 * 64];
  __shared__ ushort Bu[64 * 64];
  __shared__ int tok_s[128];

  const int tid = threadIdx.x;
  if (tid < 128) {
    int i = m0 + tid;
    tok_s[tid] = tok_list[e * LISTCAP + (i < Ne ? i : Ne - 1)];
  }
  __syncthreads();

  const int wave = tid >> 6;
  const int lane = tid & 63;
  const int rsub = lane >> 3;
  const int cchk = lane & 7;
  const int co   = (cchk ^ rsub) << 3;    // r&7 == rsub for all staged rows

  const ushort* aSrc[4];
  #pragma unroll
  for (int i = 0; i < 4; ++i)
    aSrc[i] = xb + (size_t)tok_s[wave * 32 + i * 8 + rsub] * D_MODEL + co;
  const ushort* gS = WgB + ((size_t)e * D_FFN + n0 + wave * 16 + rsub) * D_MODEL + co;
  const ushort* uS = WuB + ((size_t)e * D_FFN + n0 + wave * 16 + rsub) * D_MODEL + co;
  ushort* aD = &As[(wave * 32) * 64];
  ushort* gD = &Bg[(wave * 16) * 64];
  ushort* uD = &Bu[(wave * 16) * 64];

  const int wm   = (wave >> 1) * 64;
  const int wn   = (wave & 1) * 32;
  const int lrow = lane & 15;
  const int lq   = lane >> 4;

  f32x4 accg[4][2], accu[4][2];
  #pragma unroll
  for (int i = 0; i < 4; ++i)
    #pragma unroll
    for (int j = 0; j < 2; ++j) {
      accg[i][j] = f32x4{0.f, 0.f, 0.f, 0.f};
      accu[i][j] = f32x4{0.f, 0.f, 0.f, 0.f};
    }

  for (int k0 = 0; k0 < D_MODEL; k0 += 64) {
    #pragma unroll
    for (int i = 0; i < 4; ++i) {
      gl2lds16(aSrc[i], aD + i * 8 * 64);
      aSrc[i] += 64;
    }
    #pragma unroll
    for (int i = 0; i < 2; ++i) {
      gl2lds16(gS + (size_t)i * 8 * D_MODEL, gD + i * 8 * 64);
      gl2lds16(uS + (size_t)i * 8 * D_MODEL, uD + i * 8 * 64);
    }
    gS += 64; uS += 64;
    __syncthreads();

    #pragma unroll
    for (int kk = 0; kk < 2; ++kk) {
      const int c = kk * 4 + lq;
      bf16x8 af[4], bgf[2], buf[2];
      #pragma unroll
      for (int mi = 0; mi < 4; ++mi) {
        int r = wm + mi * 16 + lrow;
        af[mi] = *(const bf16x8*)&As[r * 64 + ((c ^ (r & 7)) << 3)];
      }
      #pragma unroll
      for (int ni = 0; ni < 2; ++ni) {
        int r = wn + ni * 16 + lrow;
        int off = r * 64 + ((c ^ (r & 7)) << 3);
        bgf[ni] = *(const bf16x8*)&Bg[off];
        buf[ni] = *(const bf16x8*)&Bu[off];
      }
      #pragma unroll
      for (int mi = 0; mi < 4; ++mi)
        #pragma unroll
        for (int ni = 0; ni < 2; ++ni) {
          accg[mi][ni] = __builtin_amdgcn_mfma_f32_16x16x32_bf16(af[mi], bgf[ni], accg[mi][ni], 0, 0, 0);
          accu[mi][ni] = __builtin_amdgcn_mfma_f32_16x16x32_bf16(af[mi], buf[ni], accu[mi][ni], 0, 0, 0);
        }
    }
    __syncthreads();
  }

  const int rowbase = rowoff + m0;
  #pragma unroll
  for (int mi = 0; mi < 4; ++mi)
    #pragma unroll
    for (int r4 = 0; r4 < 4; ++r4) {
      int m = wm + mi * 16 + lq * 4 + r4;
      if (m0 + m < Ne) {
        ushort* hr = H + (size_t)(rowbase + m) * D_FFN + n0 + wn + lrow;
        #pragma unroll
        for (int ni = 0; ni < 2; ++ni) {
          float g = accg[mi][ni][r4];
          float u = accu[mi][ni][r4];
          float h = g / (1.f + __expf(-g)) * u;
          hr[ni * 16] = f2bf(h);
        }
      }
    }
}

// Down grouped GEMM -> Y rows (bf16, unweighted). 128x128 tile, BK=64.
__global__ __launch_bounds__(256, 3) void down3_kernel(
    const ushort* __restrict__ H, const ushort* __restrict__ WdB,
    const int* __restrict__ counts, ushort* __restrict__ Y)
{
  const int e  = blockIdx.z;
  const int Ne = counts[e];
  const int m0 = blockIdx.y * 128;
  if (m0 >= Ne) return;
  const int n0 = blockIdx.x * 128;

  int rowoff = 0;
  for (int j = 0; j < e; ++j) rowoff += counts[j];
  const int rowbase = rowoff + m0;

  __shared__ ushort As[128 * 64];
  __shared__ ushort Bd[128 * 64];

  const int tid  = threadIdx.x;
  const int wave = tid >> 6;
  const int lane = tid & 63;
  const int rsub = lane >> 3;
  const int cchk = lane & 7;
  const int co   = (cchk ^ rsub) << 3;

  const ushort* aS = H   + (size_t)(rowbase + wave * 32 + rsub) * D_FFN + co;
  const ushort* bS = WdB + (size_t)(e * D_MODEL + n0 + wave * 32 + rsub) * D_FFN + co;
  ushort* aD = &As[(wave * 32) * 64];
  ushort* bD = &Bd[(wave * 32) * 64];

  const int wm   = (wave >> 1) * 64;
  const int wn   = (wave & 1) * 64;
  const int lrow = lane & 15;
  const int lq   = lane >> 4;

  f32x4 acc[4][4];
  #pragma unroll
  for (int i = 0; i < 4; ++i)
    #pragma unroll
    for (int j = 0; j < 4; ++j) acc[i][j] = f32x4{0.f, 0.f, 0.f, 0.f};

  for (int k0 = 0; k0 < D_FFN; k0 += 64) {
    #pragma unroll
    for (int i = 0; i < 4; ++i) {
      gl2lds16(aS + (size_t)i * 8 * D_FFN, aD + i * 8 * 64);
      gl2lds16(bS + (size_t)i * 8 * D_FFN, bD + i * 8 * 64);
    }
    aS += 64; bS += 64;
    __syncthreads();

    #pragma unroll
    for (int kk = 0; kk < 2; ++kk) {
      const int c = kk * 4 + lq;
      bf16x8 af[4], bf[4];
      #pragma unroll
      for (int mi = 0; mi < 4; ++mi) {
        int r = wm + mi * 16 + lrow;
        af[mi] = *(const bf16x8*)&As[r * 64 + ((c ^ (r & 7)) << 3)];
      }
      #pragma unroll
      for (int ni = 0; ni < 4; ++ni) {
        int r = wn + ni * 16 + lrow;
        bf[ni] = *(const bf16x8*)&Bd[r * 64 + ((c ^ (r & 7)) << 3)];
      }
      #pragma unroll
      for (int mi = 0; mi < 4; ++mi)
        #pragma unroll
        for (int ni = 0; ni < 4; ++ni)
          acc[mi][ni] = __builtin_amdgcn_mfma_f32_16x16x32_bf16(af[mi], bf[ni], acc[mi][ni], 0, 0, 0);
    }
    __syncthreads();
  }

  #pragma unroll
  for (int mi = 0; mi < 4; ++mi)
    #pragma unroll
    for (int r4 = 0; r4 < 4; ++r4) {
      int m = wm + mi * 16 + lq * 4 + r4;
      if (m0 + m < Ne) {
        ushort* yr = Y + (size_t)(rowbase + m) * D_MODEL + n0 + wn + lrow;
        #pragma unroll
        for (int ni = 0; ni < 4; ++ni)
          yr[ni * 16] = f2bf(acc[mi][ni][r4]);
      }
    }
}

// Combine the 2 expert rows per token + LayerNorm -> out (fp32).
__global__ __launch_bounds__(256) void combine_ln3_kernel(
    const ushort* __restrict__ Y, const int* __restrict__ slots,
    const float* __restrict__ wts, const int* __restrict__ counts,
    const float* __restrict__ gamma, const float* __restrict__ beta,
    float* __restrict__ out)
{
  const int token = blockIdx.x;
  const int t = threadIdx.x;

  __shared__ int offs_s[N_EXP];
  if (t == 0) {
    int s = 0;
    #pragma unroll
    for (int j = 0; j < N_EXP; ++j) { offs_s[j] = s; s += counts[j]; }
  }
  __syncthreads();

  const int s0 = slots[token * 2], s1 = slots[token * 2 + 1];
  const float w0 = wts[token * 2], w1 = wts[token * 2 + 1];
  const int r0 = offs_s[s0 >> 12] + (s0 & (LISTCAP - 1));
  const int r1 = offs_s[s1 >> 12] + (s1 & (LISTCAP - 1));

  ushort4 a = *(const ushort4*)(Y + (size_t)r0 * D_MODEL + t * 4);
  ushort4 b = *(const ushort4*)(Y + (size_t)r1 * D_MODEL + t * 4);
  float4 v;
  v.x = w0 * bf2f(a.x) + w1 * bf2f(b.x);
  v.y = w0 * bf2f(a.y) + w1 * bf2f(b.y);
  v.z = w0 * bf2f(a.z) + w1 * bf2f(b.z);
  v.w = w0 * bf2f(a.w) + w1 * bf2f(b.w);

  float s = v.x + v.y + v.z + v.w;
  #pragma unroll
  for (int o = 32; o > 0; o >>= 1) s += __shfl_xor(s, o, 64);
  __shared__ float red[4];
  const int wave = t >> 6, lane = t & 63;
  if (lane == 0) red[wave] = s;
  __syncthreads();
  float mean = (red[0] + red[1] + red[2] + red[3]) * (1.f / D_MODEL);

  float dx = v.x - mean, dy = v.y - mean, dz = v.z - mean, dw = v.w - mean;
  float ss = dx * dx + dy * dy + dz * dz + dw * dw;
  #pragma unroll
  for (int o = 32; o > 0; o >>= 1) ss += __shfl_xor(ss, o, 64);
  __syncthreads();
  if (lane == 0) red[wave] = ss;
  __syncthreads();
  float var = (red[0] + red[1] + red[2] + red[3]) * (1.f / D_MODEL);
  float rs  = rsqrtf(var + 1e-5f);

  float4 g = ((const float4*)gamma)[t];
  float4 bb = ((const float4*)beta)[t];
  float4 o4;
  o4.x = dx * rs * g.x + bb.x;
  o4.y = dy * rs * g.y + bb.y;
  o4.z = dz * rs * g.z + bb.z;
  o4.w = dw * rs * g.w + bb.w;
  ((float4*)(out + (size_t)token * D_MODEL))[t] = o4;
}

// ======================= FALLBACK (round-1, known-correct) ==================
__global__ __launch_bounds__(64) void router_kernel(
    const float* __restrict__ x, const float* __restrict__ wr,
    ushort* __restrict__ xb, int* __restrict__ counts,
    int* __restrict__ tok_list, float* __restrict__ wt_list)
{
  const int token = blockIdx.x;
  const int lane  = threadIdx.x;
  const float* xr = x + (size_t)token * D_MODEL;
  float xv[16];
  #pragma unroll
  for (int j = 0; j < 16; ++j) xv[j] = xr[j * 64 + lane];
  ushort* xbr = xb + (size_t)token * D_MODEL;
  #pragma unroll
  for (int j = 0; j < 16; ++j) xbr[j * 64 + lane] = f2bf(xv[j]);
  float logit[N_EXP];
  #pragma unroll
  for (int e = 0; e < N_EXP; ++e) {
    const float* w = wr + e * D_MODEL;
    float p = 0.f;
    #pragma unroll
    for (int j = 0; j < 16; ++j) p += xv[j] * w[j * 64 + lane];
    #pragma unroll
    for (int o = 32; o > 0; o >>= 1) p += __shfl_xor(p, o, 64);
    logit[e] = p;
  }
  if (lane == 0) {
    float v0 = -1e30f, v1 = -1e30f; int i0 = 0, i1 = 0;
    #pragma unroll
    for (int e = 0; e < N_EXP; ++e) {
      float v = logit[e];
      if (v > v0)      { v1 = v0; i1 = i0; v0 = v; i0 = e; }
      else if (v > v1) { v1 = v; i1 = e; }
    }
    float t  = expf(v1 - v0);
    float w0 = 1.f / (1.f + t);
    float w1 = t   / (1.f + t);
    int p0 = atomicAdd(&counts[i0], 1);
    tok_list[i0 * LISTCAP + p0] = token;
    wt_list[i0 * LISTCAP + p0] = w0;
    int p1 = atomicAdd(&counts[i1], 1);
    tok_list[i1 * LISTCAP + p1] = token;
    wt_list[i1 * LISTCAP + p1] = w1;
  }
}

__global__ void prefix_kernel(const int* __restrict__ counts, int* __restrict__ offsets)
{
  if (threadIdx.x == 0 && blockIdx.x == 0) {
    int s = 0;
    for (int e = 0; e < N_EXP; ++e) { offsets[e] = s; s += counts[e]; }
  }
}

__global__ __launch_bounds__(256, 2) void gateup_kernel(
    const ushort* __restrict__ xb, const float* __restrict__ wg,
    const float* __restrict__ wu, const int* __restrict__ counts,
    const int* __restrict__ offsets, const int* __restrict__ tok_list,
    ushort* __restrict__ H)
{
  const int e  = blockIdx.z;
  const int Ne = counts[e];
  const int m0 = blockIdx.y * 128;
  if (m0 >= Ne) return;
  const int n0 = blockIdx.x * 128;
  __shared__ ushort As[128][80];
  __shared__ ushort Bg[128][80];
  __shared__ ushort Bu[128][80];
  __shared__ int tok_s[128];
  const int tid = threadIdx.x;
  if (tid < 128) {
    int i = m0 + tid;
    tok_s[tid] = tok_list[e * LISTCAP + (i < Ne ? i : 0)];
  }
  __syncthreads();
  const int wave = tid >> 6;
  const int lane = tid & 63;
  const int wm   = (wave >> 1) * 64;
  const int wn   = (wave & 1) * 64;
  const int lrow = lane & 15;
  const int lk   = (lane >> 4) * 8;
  f32x4 accg[4][4], accu[4][4];
  #pragma unroll
  for (int i = 0; i < 4; ++i)
    #pragma unroll
    for (int j = 0; j < 4; ++j) {
      accg[i][j] = f32x4{0.f, 0.f, 0.f, 0.f};
      accu[i][j] = f32x4{0.f, 0.f, 0.f, 0.f};
    }
  const size_t wbase = ((size_t)e * D_FFN + n0) * D_MODEL;
  for (int k0 = 0; k0 < D_MODEL; k0 += 64) {
    #pragma unroll
    for (int r = 0; r < 4; ++r) {
      int idx = tid + r * 256;
      int row = idx >> 3;
      int c8  = (idx & 7) * 8;
      const ushort* src = xb + (size_t)tok_s[row] * D_MODEL + k0 + c8;
      *(uint4*)(&As[row][c8]) = *(const uint4*)src;
    }
    #pragma unroll
    for (int r = 0; r < 8; ++r) {
      int idx = tid + r * 256;
      int row = idx >> 4;
      int c4  = (idx & 15) * 4;
      const size_t off = wbase + (size_t)row * D_MODEL + k0 + c4;
      const float4 g = *(const float4*)(wg + off);
      const float4 u = *(const float4*)(wu + off);
      ushort4 gb; gb.x = f2bf(g.x); gb.y = f2bf(g.y); gb.z = f2bf(g.z); gb.w = f2bf(g.w);
      ushort4 ub; ub.x = f2bf(u.x); ub.y = f2bf(u.y); ub.z = f2bf(u.z); ub.w = f2bf(u.w);
      *(ushort4*)(&Bg[row][c4]) = gb;
      *(ushort4*)(&Bu[row][c4]) = ub;
    }
    __syncthreads();
    #pragma unroll
    for (int kk = 0; kk < 64; kk += 32) {
      bf16x8 af[4], bgf[4], buf[4];
      #pragma unroll
      for (int mi = 0; mi < 4; ++mi)
        af[mi] = *(const bf16x8*)(&As[wm + mi * 16 + lrow][kk + lk]);
      #pragma unroll
      for (int ni = 0; ni < 4; ++ni) {
        bgf[ni] = *(const bf16x8*)(&Bg[wn + ni * 16 + lrow][kk + lk]);
        buf[ni] = *(const bf16x8*)(&Bu[wn + ni * 16 + lrow][kk + lk]);
      }
      #pragma unroll
      for (int mi = 0; mi < 4; ++mi)
        #pragma unroll
        for (int ni = 0; ni < 4; ++ni) {
          accg[mi][ni] = __builtin_amdgcn_mfma_f32_16x16x32_bf16(af[mi], bgf[ni], accg[mi][ni], 0, 0, 0);
          accu[mi][ni] = __builtin_amdgcn_mfma_f32_16x16x32_bf16(af[mi], buf[ni], accu[mi][ni], 0, 0, 0);
        }
    }
    __syncthreads();
  }
  const int row_base = offsets[e] + m0;
  #pragma unroll
  for (int mi = 0; mi < 4; ++mi)
    #pragma unroll
    for (int ni = 0; ni < 4; ++ni)
      #pragma unroll
      for (int r4 = 0; r4 < 4; ++r4) {
        int m = wm + mi * 16 + (lane >> 4) * 4 + r4;
        if (m0 + m < Ne) {
          int n = wn + ni * 16 + (lane & 15);
          float g = accg[mi][ni][r4];
          float u = accu[mi][ni][r4];
          float h = g / (1.f + __expf(-g)) * u;
          H[(size_t)(row_base + m) * D_FFN + (n0 + n)] = f2bf(h);
        }
      }
}

__global__ __launch_bounds__(256, 2) void down_kernel(
    const ushort* __restrict__ H, const float* __restrict__ wd,
    const int* __restrict__ counts, const int* __restrict__ offsets,
    const int* __restrict__ tok_list, const float* __restrict__ wt_list,
    float* __restrict__ out)
{
  const int e  = blockIdx.z;
  const int Ne = counts[e];
  const int m0 = blockIdx.y * 128;
  if (m0 >= Ne) return;
  const int n0 = blockIdx.x * 128;
  __shared__ ushort As[128][80];
  __shared__ ushort Bd[128][80];
  __shared__ int   tok_s[128];
  __shared__ float wt_s[128];
  const int tid = threadIdx.x;
  if (tid < 128) {
    int i  = m0 + tid;
    int ok = (i < Ne);
    tok_s[tid] = tok_list[e * LISTCAP + (ok ? i : 0)];
    wt_s[tid]  = ok ? wt_list[e * LISTCAP + i] : 0.f;
  }
  __syncthreads();
  const int wave = tid >> 6;
  const int lane = tid & 63;
  const int wm   = (wave >> 1) * 64;
  const int wn   = (wave & 1) * 64;
  const int lrow = lane & 15;
  const int lk   = (lane >> 4) * 8;
  const int row_base = offsets[e] + m0;
  f32x4 acc[4][4];
  #pragma unroll
  for (int i = 0; i < 4; ++i)
    #pragma unroll
    for (int j = 0; j < 4; ++j) acc[i][j] = f32x4{0.f, 0.f, 0.f, 0.f};
  const size_t wdbase = ((size_t)e * D_MODEL + n0) * D_FFN;
  for (int k0 = 0; k0 < D_FFN; k0 += 64) {
    #pragma unroll
    for (int r = 0; r < 4; ++r) {
      int idx = tid + r * 256;
      int row = idx >> 3;
      int c8  = (idx & 7) * 8;
      const ushort* src = H + (size_t)(row_base + row) * D_FFN + k0 + c8;
      *(uint4*)(&As[row][c8]) = *(const uint4*)src;
    }
    #pragma unroll
    for (int r = 0; r < 8; ++r) {
      int idx = tid + r * 256;
      int row = idx >> 4;
      int c4  = (idx & 15) * 4;
      const float4 d = *(const float4*)(wd + wdbase + (size_t)row * D_FFN + k0 + c4);
      ushort4 db; db.x = f2bf(d.x); db.y = f2bf(d.y); db.z = f2bf(d.z); db.w = f2bf(d.w);
      *(ushort4*)(&Bd[row][c4]) = db;
    }
    __syncthreads();
    #pragma unroll
    for (int kk = 0; kk < 64; kk += 32) {
      bf16x8 af[4], bdf[4];
      #pragma unroll
      for (int mi = 0; mi < 4; ++mi)
        af[mi] = *(const bf16x8*)(&As[wm + mi * 16 + lrow][kk + lk]);
      #pragma unroll
      for (int ni = 0; ni < 4; ++ni)
        bdf[ni] = *(const bf16x8*)(&Bd[wn + ni * 16 + lrow][kk + lk]);
      #pragma unroll
      for (int mi = 0; mi < 4; ++mi)
        #pragma unroll
        for (int ni = 0; ni < 4; ++ni)
          acc[mi][ni] = __builtin_amdgcn_mfma_f32_16x16x32_bf16(af[mi], bdf[ni], acc[mi][ni], 0, 0, 0);
    }
    __syncthreads();
  }
  #pragma unroll
  for (int mi = 0; mi < 4; ++mi)
    #pragma unroll
    for (int ni = 0; ni < 4; ++ni)
      #pragma unroll
      for (int r4 = 0; r4 < 4; ++r4) {
        int m = wm + mi * 16 + (lane >> 4) * 4 + r4;
        if (m0 + m < Ne) {
          int n = wn + ni * 16 + (lane & 15);
          float v = acc[mi][ni][r4] * wt_s[m];
          atomicAdd(&out[(size_t)tok_s[m] * D_MODEL + (n0 + n)], v);
        }
      }
}

__global__ __launch_bounds__(256) void ln_kernel(
    float* __restrict__ out, const float* __restrict__ gamma,
    const float* __restrict__ beta)
{
  const int row = blockIdx.x;
  const int t   = threadIdx.x;
  float* rp = out + (size_t)row * D_MODEL;
  float4 v = ((const float4*)rp)[t];
  float s = v.x + v.y + v.z + v.w;
  #pragma unroll
  for (int o = 32; o > 0; o >>= 1) s += __shfl_xor(s, o, 64);
  __shared__ float red[4];
  const int wave = t >> 6, lane = t & 63;
  if (lane == 0) red[wave] = s;
  __syncthreads();
  float mean = (red[0] + red[1] + red[2] + red[3]) * (1.f / D_MODEL);
  float dx = v.x - mean, dy = v.y - mean, dz = v.z - mean, dw = v.w - mean;
  float ss = dx * dx + dy * dy + dz * dz + dw * dw;
  #pragma unroll
  for (int o = 32; o > 0; o >>= 1) ss += __shfl_xor(ss, o, 64);
  __syncthreads();
  if (lane == 0) red[wave] = ss;
  __syncthreads();
  float var = (red[0] + red[1] + red[2] + red[3]) * (1.f / D_MODEL);
  float rs  = rsqrtf(var + 1e-5f);
  float4 g = ((const float4*)gamma)[t];
  float4 b = ((const float4*)beta)[t];
  float4 o4;
  o4.x = dx * rs * g.x + b.x;
  o4.y = dy * rs * g.y + b.y;
  o4.z = dz * rs * g.z + b.z;
  o4.w = dw * rs * g.w + b.w;
  ((float4*)rp)[t] = o4;
}

// ======================= Launch =============================================
extern "C" void kernel_launch(void* const* d_in, const int* in_sizes, int n_in,
                              void* d_out, int out_size, void* d_ws, size_t ws_size,
                              hipStream_t stream) {
  const float* x        = (const float*)d_in[0];
  const float* w_router = (const float*)d_in[1];
  const float* w_gate   = (const float*)d_in[2];
  const float* w_up     = (const float*)d_in[3];
  const float* w_down   = (const float*)d_in[4];
  const float* ln_gamma = (const float*)d_in[5];
  const float* ln_beta  = (const float*)d_in[6];
  float* out = (float*)d_out;
  char* ws = (char*)d_ws;

  const size_t META = 262144;
  const size_t NEED = META + 3 * (size_t)W_ELEM * 2
                      + (size_t)TOKENS * D_MODEL * 2
                      + (size_t)ROWS_PAD * D_FFN * 2;   // ~143.4 MB

  if (ws_size >= NEED) {
    int*   counts   = (int*)ws;
    int*   tok_list = (int*)(ws + 4096);
    int*   slots    = (int*)(ws + 4096 + 131072);
    float* wts      = (float*)(ws + 4096 + 131072 + 32768);
    int*   eids     = (int*)(ws + 4096 + 131072 + 32768 + 32768);
    ushort* WgB = (ushort*)(ws + META);
    ushort* WuB = WgB + W_ELEM;
    ushort* WdB = WuB + W_ELEM;
    ushort* xb  = WdB + W_ELEM;
    ushort* H   = xb + (size_t)TOKENS * D_MODEL;
    ushort* Y   = WgB;   // alias: WgB/WuB dead after gateup3

    router_a_kernel<<<TOKENS / 4, 256, 0, stream>>>(x, w_router, xb, eids, wts);
    build_lists_kernel<<<N_EXP, 1024, 0, stream>>>(eids, counts, tok_list, slots);
    convert3_kernel<<<3 * 8192, 256, 0, stream>>>(w_gate, w_up, w_down, WgB);
    gateup3_kernel<<<dim3(D_FFN / 64, 32, N_EXP), 256, 0, stream>>>(
        xb, WgB, WuB, counts, tok_list, H);
    down3_kernel<<<dim3(D_MODEL / 128, 32, N_EXP), 256, 0, stream>>>(
        H, WdB, counts, Y);
    combine_ln3_kernel<<<TOKENS, 256, 0, stream>>>(Y, slots, wts, counts,
                                                   ln_gamma, ln_beta, out);
  } else {
    // round-1 fallback
    int*   counts   = (int*)ws;
    int*   offsets  = counts + 8;
    int*   tok_list = (int*)(ws + 256);
    float* wt_list  = (float*)(ws + 256 + LISTCAP * N_EXP * 4);
    ushort* xb      = (ushort*)(ws + 256 + LISTCAP * N_EXP * 8);
    ushort* H       = xb + (size_t)TOKENS * D_MODEL;

    hipMemsetAsync(counts, 0, 64, stream);
    hipMemsetAsync(out, 0, (size_t)TOKENS * D_MODEL * sizeof(float), stream);
    router_kernel<<<TOKENS, 64, 0, stream>>>(x, w_router, xb, counts, tok_list, wt_list);
    prefix_kernel<<<1, 64, 0, stream>>>(counts, offsets);
    gateup_kernel<<<dim3(D_FFN / 128, 32, N_EXP), 256, 0, stream>>>(
        xb, w_gate, w_up, counts, offsets, tok_list, H);
    down_kernel<<<dim3(D_MODEL / 128, 32, N_EXP), 256, 0, stream>>>(
        H, w_down, counts, offsets, tok_list, wt_list, out);
    ln_kernel<<<TOKENS, 256, 0, stream>>>(out, ln_gamma, ln_beta);
  }
}